// Round 1
// baseline (294.259 us; speedup 1.0000x reference)
//
#include <hip/hip_runtime.h>
#include <math.h>

#define N_NODES 2048
#define T_WIN 5
#define D_EMB 64
#define TOPK 21
#define B_BATCH 32
#define BN_TOTAL (B_BATCH * N_NODES)   // 65536
#define EPS_BN 1e-5f
#define NEG_SLOPE 0.2f

// ---------------- wave-level helpers (wave = 64 on gfx950) ----------------
__device__ __forceinline__ float wave_sum(float v) {
#pragma unroll
    for (int off = 32; off > 0; off >>= 1) v += __shfl_xor(v, off, 64);
    return v;
}
__device__ __forceinline__ float wave_max(float v) {
#pragma unroll
    for (int off = 32; off > 0; off >>= 1) v = fmaxf(v, __shfl_xor(v, off, 64));
    return v;
}

// ---------------- K1: per-node precompute: norm, emb-half of e_src/e_dst ----
__global__ __launch_bounds__(64) void k_node_pre(
    const float* __restrict__ emb, const float* __restrict__ a_src,
    const float* __restrict__ a_dst, float* __restrict__ norms,
    float* __restrict__ es_emb, float* __restrict__ ed_emb) {
    int n = blockIdx.x;
    int d = threadIdx.x;
    float e = emb[n * D_EMB + d];
    float s2 = wave_sum(e * e);
    float es = wave_sum(e * a_src[D_EMB + d]);
    float ed = wave_sum(e * a_dst[D_EMB + d]);
    if (d == 0) {
        norms[n] = sqrtf(s2);
        es_emb[n] = es;
        ed_emb[n] = ed;
    }
}

// ---------------- K2: cosine rows + top-21 selection ------------------------
// 4 rows per block (one per wave). Phase A: cooperative cos-row fill into LDS.
// Phase B: each wave runs 21 iterations of argmax-with-lower-index-tiebreak
// (matches jax.lax.top_k tie semantics). Lane l owns entries j = l + 64k, so
// invalidation writes are only re-read by the owning lane -> no barriers.
__global__ __launch_bounds__(256) void k_topk(
    const float* __restrict__ emb, const float* __restrict__ norms,
    int* __restrict__ idxbuf) {
    __shared__ float cosrow[4][N_NODES];   // 32 KB
    __shared__ float embi[4][D_EMB];
    __shared__ float nI[4];

    int tid = threadIdx.x;
    int i0 = blockIdx.x * 4;

    {   // load the block's 4 emb rows + their norms
        int r = tid >> 6, d = tid & 63;
        embi[r][d] = emb[(i0 + r) * D_EMB + d];
        if (tid < 4) nI[tid] = norms[i0 + tid];
    }
    __syncthreads();

    // Phase A: fill 4 cos rows cooperatively
    for (int j = tid; j < N_NODES; j += 256) {
        const float4* ej = (const float4*)(emb + (size_t)j * D_EMB);
        float nj = norms[j];
        float dr0 = 0.f, dr1 = 0.f, dr2 = 0.f, dr3 = 0.f;
#pragma unroll
        for (int c = 0; c < 16; c++) {
            float4 v = ej[c];
            float4 w0 = ((const float4*)embi[0])[c];
            float4 w1 = ((const float4*)embi[1])[c];
            float4 w2 = ((const float4*)embi[2])[c];
            float4 w3 = ((const float4*)embi[3])[c];
            dr0 += v.x * w0.x + v.y * w0.y + v.z * w0.z + v.w * w0.w;
            dr1 += v.x * w1.x + v.y * w1.y + v.z * w1.z + v.w * w1.w;
            dr2 += v.x * w2.x + v.y * w2.y + v.z * w2.z + v.w * w2.w;
            dr3 += v.x * w3.x + v.y * w3.y + v.z * w3.z + v.w * w3.w;
        }
        cosrow[0][j] = dr0 / (nI[0] * nj);
        cosrow[1][j] = dr1 / (nI[1] * nj);
        cosrow[2][j] = dr2 / (nI[2] * nj);
        cosrow[3][j] = dr3 / (nI[3] * nj);
    }
    __syncthreads();

    // Phase B: per-wave top-21 selection on its own row
    int wid = tid >> 6, lane = tid & 63;
    int i = i0 + wid;
    for (int it = 0; it < TOPK; it++) {
        float bv = -3e38f;
        int bj = 0x7fffffff;
#pragma unroll
        for (int k = 0; k < N_NODES / 64; k++) {
            int j = lane + 64 * k;
            float v = cosrow[wid][j];
            if (v > bv || (v == bv && j < bj)) { bv = v; bj = j; }
        }
#pragma unroll
        for (int off = 32; off > 0; off >>= 1) {
            float ov = __shfl_xor(bv, off, 64);
            int oj = __shfl_xor(bj, off, 64);
            if (ov > bv || (ov == bv && oj < bj)) { bv = ov; bj = oj; }
        }
        if ((bj & 63) == lane) cosrow[wid][bj] = -3e38f;  // owner invalidates
        if (lane == 0) idxbuf[i * TOPK + it] = bj;
    }
}

// ---------------- K3: h = x@W^T + Wb ; e_src/e_dst --------------------------
__global__ __launch_bounds__(256) void k_h(
    const float* __restrict__ x, const float* __restrict__ W,
    const float* __restrict__ Wb, const float* __restrict__ a_src,
    const float* __restrict__ a_dst, const float* __restrict__ es_emb,
    const float* __restrict__ ed_emb, float* __restrict__ h,
    float* __restrict__ e_src, float* __restrict__ e_dst) {
    int wid = threadIdx.x >> 6, lane = threadIdx.x & 63;
    int node = blockIdx.x * 4 + wid;          // node = b*N + n
    int n = node & (N_NODES - 1);
    const float* xp = x + (size_t)node * T_WIN;
    float x0 = xp[0], x1 = xp[1], x2 = xp[2], x3 = xp[3], x4 = xp[4];
    const float* wp = W + lane * T_WIN;       // W is [D,T] row-major
    float hv = Wb[lane] + x0 * wp[0] + x1 * wp[1] + x2 * wp[2] + x3 * wp[3] + x4 * wp[4];
    h[(size_t)node * D_EMB + lane] = hv;
    float es = wave_sum(hv * a_src[lane]);
    float ed = wave_sum(hv * a_dst[lane]);
    if (lane == 0) {
        e_src[node] = es + es_emb[n];
        e_dst[node] = ed + ed_emb[n];
    }
}

// ---------------- K4: attention message passing + pre-BN output + stats -----
__global__ __launch_bounds__(256) void k_msg(
    const int* __restrict__ idxbuf, const float* __restrict__ e_src,
    const float* __restrict__ e_dst, const float* __restrict__ h,
    const float* __restrict__ emb, float* __restrict__ obuf,
    float* __restrict__ stats, float* __restrict__ stats2) {
    int wid = threadIdx.x >> 6, lane = threadIdx.x & 63;
    int gw = blockIdx.x * 4 + wid;            // global wave id: 0..4095
    float acc = 0.f, acc2 = 0.f;

    for (int node = gw; node < BN_TOTAL; node += 4096) {
        int b = node >> 11;                   // node / N
        int i = node & (N_NODES - 1);
        // lane k<21 handles neighbor k
        int jk = idxbuf[i * TOPK + (lane < TOPK ? lane : 0)];
        float ev = e_src[node] + e_dst[b * N_NODES + jk];
        ev = ev > 0.f ? ev : NEG_SLOPE * ev;  // leaky_relu
        float evm = (lane < TOPK) ? ev : -3e38f;
        float m = wave_max(evm);
        float w = (lane < TOPK) ? __expf(ev - m) : 0.f;
        float s = wave_sum(w);
        float alpha = w / s;

        const float* hb = h + (size_t)b * N_NODES * D_EMB;
        float z = 0.f;
#pragma unroll
        for (int k = 0; k < TOPK; k++) {
            float a = __shfl(alpha, k, 64);
            int j = __shfl(jk, k, 64);
            z += a * hb[(size_t)j * D_EMB + lane];
        }
        float o = fmaxf(z, 0.f) * emb[i * D_EMB + lane];
        obuf[(size_t)node * D_EMB + lane] = o;
        acc += o;
        acc2 += o * o;
    }

    // block-level channel partials -> one atomic per channel per block
    __shared__ float sa[4][D_EMB], sb[4][D_EMB];
    sa[wid][lane] = acc;
    sb[wid][lane] = acc2;
    __syncthreads();
    if (wid == 0) {
        float t = sa[0][lane] + sa[1][lane] + sa[2][lane] + sa[3][lane];
        float t2 = sb[0][lane] + sb[1][lane] + sb[2][lane] + sb[3][lane];
        atomicAdd(&stats[lane], t);
        atomicAdd(&stats2[lane], t2);
    }
}

// ---------------- K5: BN apply + relu + fc ---------------------------------
__global__ __launch_bounds__(256) void k_out(
    const float* __restrict__ obuf, const float* __restrict__ stats,
    const float* __restrict__ stats2, const float* __restrict__ gamma,
    const float* __restrict__ beta, const float* __restrict__ fc_w,
    const float* __restrict__ fc_b, float* __restrict__ out) {
    int wid = threadIdx.x >> 6, lane = threadIdx.x & 63;
    int node = blockIdx.x * 4 + wid;
    const float invM = 1.0f / (float)BN_TOTAL;
    float mean = stats[lane] * invM;
    float var = stats2[lane] * invM - mean * mean;
    float inv = rsqrtf(var + EPS_BN);
    float o = obuf[(size_t)node * D_EMB + lane];
    float v = (o - mean) * inv * gamma[lane] + beta[lane];
    v = fmaxf(v, 0.f);
    float p = wave_sum(v * fc_w[lane]);
    if (lane == 0) out[node] = p + fc_b[0];
}

// ---------------- launch ----------------------------------------------------
extern "C" void kernel_launch(void* const* d_in, const int* in_sizes, int n_in,
                              void* d_out, int out_size, void* d_ws, size_t ws_size,
                              hipStream_t stream) {
    const float* x     = (const float*)d_in[0];   // [B,N,T]
    const float* emb   = (const float*)d_in[1];   // [N,D]
    const float* W     = (const float*)d_in[2];   // [D,T]
    const float* Wb    = (const float*)d_in[3];   // [D]
    const float* a_src = (const float*)d_in[4];   // [2D]
    const float* a_dst = (const float*)d_in[5];   // [2D]
    const float* gamma = (const float*)d_in[6];   // [D]
    const float* beta  = (const float*)d_in[7];   // [D]
    const float* fc_w  = (const float*)d_in[8];   // [1,D]
    const float* fc_b  = (const float*)d_in[9];   // [1]
    float* out = (float*)d_out;                   // [B,N]

    char* ws = (char*)d_ws;
    // workspace layout (256B-aligned chunks)
    float* stats  = (float*)(ws + 0);             // 64 f
    float* stats2 = (float*)(ws + 256);           // 64 f
    int*   idxbuf = (int*)  (ws + 512);           // N*21 ints  = 172032 B
    float* norms  = (float*)(ws + 172544);        // N f
    float* es_emb = (float*)(ws + 180736);        // N f
    float* ed_emb = (float*)(ws + 188928);        // N f
    float* e_src  = (float*)(ws + 197120);        // B*N f
    float* e_dst  = (float*)(ws + 459264);        // B*N f
    float* h      = (float*)(ws + 721408);        // B*N*D f = 16 MB
    float* obuf   = (float*)(ws + 17498624);      // B*N*D f = 16 MB
    // total: 34,275,840 bytes

    hipMemsetAsync(stats, 0, 2 * 256, stream);    // zero stats+stats2

    k_node_pre<<<N_NODES, 64, 0, stream>>>(emb, a_src, a_dst, norms, es_emb, ed_emb);
    k_topk<<<N_NODES / 4, 256, 0, stream>>>(emb, norms, idxbuf);
    k_h<<<BN_TOTAL / 4, 256, 0, stream>>>(x, W, Wb, a_src, a_dst, es_emb, ed_emb,
                                          h, e_src, e_dst);
    k_msg<<<1024, 256, 0, stream>>>(idxbuf, e_src, e_dst, h, emb, obuf, stats, stats2);
    k_out<<<BN_TOTAL / 4, 256, 0, stream>>>(obuf, stats, stats2, gamma, beta,
                                            fc_w, fc_b, out);
}

// Round 2
// 227.472 us; speedup vs baseline: 1.2936x; 1.2936x over previous
//
#include <hip/hip_runtime.h>
#include <math.h>

#define N_NODES 2048
#define T_WIN 5
#define D_EMB 64
#define TOPK 21
#define B_BATCH 32
#define BN_TOTAL (B_BATCH * N_NODES)   // 65536
#define EPS_BN 1e-5f
#define NEG_SLOPE 0.2f

// ---------------- wave-level helpers (wave = 64 on gfx950) ----------------
__device__ __forceinline__ float wave_sum(float v) {
#pragma unroll
    for (int off = 32; off > 0; off >>= 1) v += __shfl_xor(v, off, 64);
    return v;
}
__device__ __forceinline__ float wave_max(float v) {
#pragma unroll
    for (int off = 32; off > 0; off >>= 1) v = fmaxf(v, __shfl_xor(v, off, 64));
    return v;
}

// ---------------- K1: per-node precompute: norm, emb-half of e_src/e_dst ----
__global__ __launch_bounds__(64) void k_node_pre(
    const float* __restrict__ emb, const float* __restrict__ a_src,
    const float* __restrict__ a_dst, float* __restrict__ norms,
    float* __restrict__ es_emb, float* __restrict__ ed_emb) {
    int n = blockIdx.x;
    int d = threadIdx.x;
    float e = emb[n * D_EMB + d];
    float s2 = wave_sum(e * e);
    float es = wave_sum(e * a_src[D_EMB + d]);
    float ed = wave_sum(e * a_dst[D_EMB + d]);
    if (d == 0) {
        norms[n] = sqrtf(s2);
        es_emb[n] = es;
        ed_emb[n] = ed;
    }
}

// ---------------- K2: cosine rows + top-21 selection ------------------------
// Phase A: cooperative cos-row fill into LDS (4 rows per block, one per wave).
// Phase B: REGISTER-resident selection. Each lane pulls its 32 row entries
// from LDS once (stride-64 -> bank = lane%32, 2-way conflict = free on
// gfx950) and packs each into a sortable u64 key:
//     key = (monotonic(f32) << 32) | (u32)~j
// so u64-max == (max value, lower index on ties) — matches jax.lax.top_k
// tie semantics. The 21-iteration selection loop is then pure VALU
// (local 31-op max tree + 6-step u64 shuffle reduce + invalidate), no
// dependent LDS reads — the round-1 kernel serialized 672 ~120-cycle LDS
// reads per wave here at 11% occupancy.
__global__ __launch_bounds__(256) void k_topk(
    const float* __restrict__ emb, const float* __restrict__ norms,
    int* __restrict__ idxbuf) {
    __shared__ float cosrow[4][N_NODES];   // 32 KB
    __shared__ float embi[4][D_EMB];
    __shared__ float nI[4];

    int tid = threadIdx.x;
    int i0 = blockIdx.x * 4;

    {   // load the block's 4 emb rows + their norms
        int r = tid >> 6, d = tid & 63;
        embi[r][d] = emb[(i0 + r) * D_EMB + d];
        if (tid < 4) nI[tid] = norms[i0 + tid];
    }
    __syncthreads();

    // Phase A: fill 4 cos rows cooperatively
    for (int j = tid; j < N_NODES; j += 256) {
        const float4* ej = (const float4*)(emb + (size_t)j * D_EMB);
        float nj = norms[j];
        float dr0 = 0.f, dr1 = 0.f, dr2 = 0.f, dr3 = 0.f;
#pragma unroll
        for (int c = 0; c < 16; c++) {
            float4 v = ej[c];
            float4 w0 = ((const float4*)embi[0])[c];
            float4 w1 = ((const float4*)embi[1])[c];
            float4 w2 = ((const float4*)embi[2])[c];
            float4 w3 = ((const float4*)embi[3])[c];
            dr0 += v.x * w0.x + v.y * w0.y + v.z * w0.z + v.w * w0.w;
            dr1 += v.x * w1.x + v.y * w1.y + v.z * w1.z + v.w * w1.w;
            dr2 += v.x * w2.x + v.y * w2.y + v.z * w2.z + v.w * w2.w;
            dr3 += v.x * w3.x + v.y * w3.y + v.z * w3.z + v.w * w3.w;
        }
        cosrow[0][j] = dr0 / (nI[0] * nj);
        cosrow[1][j] = dr1 / (nI[1] * nj);
        cosrow[2][j] = dr2 / (nI[2] * nj);
        cosrow[3][j] = dr3 / (nI[3] * nj);
    }
    __syncthreads();

    // Phase B: per-wave register-resident top-21
    int wid = tid >> 6, lane = tid & 63;
    int i = i0 + wid;

    unsigned long long key[32];
#pragma unroll
    for (int k = 0; k < 32; k++) {
        int j = lane + 64 * k;
        unsigned u = __float_as_uint(cosrow[wid][j]);
        u = (u & 0x80000000u) ? ~u : (u | 0x80000000u);  // monotonic transform
        key[k] = ((unsigned long long)u << 32) | (unsigned)(~j);
    }
    // all real keys > 0 (cos >= -1 -> mono >= ~0x40000000); 0 == -inf
    for (int it = 0; it < TOPK; it++) {
        unsigned long long m = key[0];
#pragma unroll
        for (int k = 1; k < 32; k++) m = key[k] > m ? key[k] : m;
#pragma unroll
        for (int off = 32; off > 0; off >>= 1) {
            unsigned long long o = __shfl_xor(m, off, 64);
            m = o > m ? o : m;
        }
        if (lane == 0) idxbuf[i * TOPK + it] = (int)(~(unsigned)m);
#pragma unroll
        for (int k = 0; k < 32; k++) if (key[k] == m) key[k] = 0ull;
    }
}

// ---------------- K3: h = x@W^T + Wb ; e_src/e_dst --------------------------
__global__ __launch_bounds__(256) void k_h(
    const float* __restrict__ x, const float* __restrict__ W,
    const float* __restrict__ Wb, const float* __restrict__ a_src,
    const float* __restrict__ a_dst, const float* __restrict__ es_emb,
    const float* __restrict__ ed_emb, float* __restrict__ h,
    float* __restrict__ e_src, float* __restrict__ e_dst) {
    int wid = threadIdx.x >> 6, lane = threadIdx.x & 63;
    int node = blockIdx.x * 4 + wid;          // node = b*N + n
    int n = node & (N_NODES - 1);
    const float* xp = x + (size_t)node * T_WIN;
    float x0 = xp[0], x1 = xp[1], x2 = xp[2], x3 = xp[3], x4 = xp[4];
    const float* wp = W + lane * T_WIN;       // W is [D,T] row-major
    float hv = Wb[lane] + x0 * wp[0] + x1 * wp[1] + x2 * wp[2] + x3 * wp[3] + x4 * wp[4];
    h[(size_t)node * D_EMB + lane] = hv;
    float es = wave_sum(hv * a_src[lane]);
    float ed = wave_sum(hv * a_dst[lane]);
    if (lane == 0) {
        e_src[node] = es + es_emb[n];
        e_dst[node] = ed + ed_emb[n];
    }
}

// ---------------- K4: attention message passing + pre-BN output + stats -----
__global__ __launch_bounds__(256) void k_msg(
    const int* __restrict__ idxbuf, const float* __restrict__ e_src,
    const float* __restrict__ e_dst, const float* __restrict__ h,
    const float* __restrict__ emb, float* __restrict__ obuf,
    float* __restrict__ stats, float* __restrict__ stats2) {
    int wid = threadIdx.x >> 6, lane = threadIdx.x & 63;
    int gw = blockIdx.x * 4 + wid;            // global wave id: 0..4095
    float acc = 0.f, acc2 = 0.f;

    for (int node = gw; node < BN_TOTAL; node += 4096) {
        int b = node >> 11;                   // node / N
        int i = node & (N_NODES - 1);
        // lane k<21 handles neighbor k
        int jk = idxbuf[i * TOPK + (lane < TOPK ? lane : 0)];
        float ev = e_src[node] + e_dst[b * N_NODES + jk];
        ev = ev > 0.f ? ev : NEG_SLOPE * ev;  // leaky_relu
        float evm = (lane < TOPK) ? ev : -3e38f;
        float m = wave_max(evm);
        float w = (lane < TOPK) ? __expf(ev - m) : 0.f;
        float s = wave_sum(w);
        float alpha = w / s;

        const float* hb = h + (size_t)b * N_NODES * D_EMB;
        float z = 0.f;
#pragma unroll
        for (int k = 0; k < TOPK; k++) {
            float a = __shfl(alpha, k, 64);
            int j = __shfl(jk, k, 64);
            z += a * hb[(size_t)j * D_EMB + lane];
        }
        float o = fmaxf(z, 0.f) * emb[i * D_EMB + lane];
        obuf[(size_t)node * D_EMB + lane] = o;
        acc += o;
        acc2 += o * o;
    }

    // block-level channel partials -> one atomic per channel per block
    __shared__ float sa[4][D_EMB], sb[4][D_EMB];
    sa[wid][lane] = acc;
    sb[wid][lane] = acc2;
    __syncthreads();
    if (wid == 0) {
        float t = sa[0][lane] + sa[1][lane] + sa[2][lane] + sa[3][lane];
        float t2 = sb[0][lane] + sb[1][lane] + sb[2][lane] + sb[3][lane];
        atomicAdd(&stats[lane], t);
        atomicAdd(&stats2[lane], t2);
    }
}

// ---------------- K5: BN apply + relu + fc ---------------------------------
__global__ __launch_bounds__(256) void k_out(
    const float* __restrict__ obuf, const float* __restrict__ stats,
    const float* __restrict__ stats2, const float* __restrict__ gamma,
    const float* __restrict__ beta, const float* __restrict__ fc_w,
    const float* __restrict__ fc_b, float* __restrict__ out) {
    int wid = threadIdx.x >> 6, lane = threadIdx.x & 63;
    int node = blockIdx.x * 4 + wid;
    const float invM = 1.0f / (float)BN_TOTAL;
    float mean = stats[lane] * invM;
    float var = stats2[lane] * invM - mean * mean;
    float inv = rsqrtf(var + EPS_BN);
    float o = obuf[(size_t)node * D_EMB + lane];
    float v = (o - mean) * inv * gamma[lane] + beta[lane];
    v = fmaxf(v, 0.f);
    float p = wave_sum(v * fc_w[lane]);
    if (lane == 0) out[node] = p + fc_b[0];
}

// ---------------- launch ----------------------------------------------------
extern "C" void kernel_launch(void* const* d_in, const int* in_sizes, int n_in,
                              void* d_out, int out_size, void* d_ws, size_t ws_size,
                              hipStream_t stream) {
    const float* x     = (const float*)d_in[0];   // [B,N,T]
    const float* emb   = (const float*)d_in[1];   // [N,D]
    const float* W     = (const float*)d_in[2];   // [D,T]
    const float* Wb    = (const float*)d_in[3];   // [D]
    const float* a_src = (const float*)d_in[4];   // [2D]
    const float* a_dst = (const float*)d_in[5];   // [2D]
    const float* gamma = (const float*)d_in[6];   // [D]
    const float* beta  = (const float*)d_in[7];   // [D]
    const float* fc_w  = (const float*)d_in[8];   // [1,D]
    const float* fc_b  = (const float*)d_in[9];   // [1]
    float* out = (float*)d_out;                   // [B,N]

    char* ws = (char*)d_ws;
    // workspace layout (256B-aligned chunks)
    float* stats  = (float*)(ws + 0);             // 64 f
    float* stats2 = (float*)(ws + 256);           // 64 f
    int*   idxbuf = (int*)  (ws + 512);           // N*21 ints  = 172032 B
    float* norms  = (float*)(ws + 172544);        // N f
    float* es_emb = (float*)(ws + 180736);        // N f
    float* ed_emb = (float*)(ws + 188928);        // N f
    float* e_src  = (float*)(ws + 197120);        // B*N f
    float* e_dst  = (float*)(ws + 459264);        // B*N f
    float* h      = (float*)(ws + 721408);        // B*N*D f = 16 MB
    float* obuf   = (float*)(ws + 17498624);      // B*N*D f = 16 MB
    // total: 34,275,840 bytes

    hipMemsetAsync(stats, 0, 2 * 256, stream);    // zero stats+stats2

    k_node_pre<<<N_NODES, 64, 0, stream>>>(emb, a_src, a_dst, norms, es_emb, ed_emb);
    k_topk<<<N_NODES / 4, 256, 0, stream>>>(emb, norms, idxbuf);
    k_h<<<BN_TOTAL / 4, 256, 0, stream>>>(x, W, Wb, a_src, a_dst, es_emb, ed_emb,
                                          h, e_src, e_dst);
    k_msg<<<1024, 256, 0, stream>>>(idxbuf, e_src, e_dst, h, emb, obuf, stats, stats2);
    k_out<<<BN_TOTAL / 4, 256, 0, stream>>>(obuf, stats, stats2, gamma, beta,
                                            fc_w, fc_b, out);
}

// Round 3
// 226.515 us; speedup vs baseline: 1.2991x; 1.0042x over previous
//
#include <hip/hip_runtime.h>
#include <math.h>

#define N_NODES 2048
#define T_WIN 5
#define D_EMB 64
#define TOPK 21
#define B_BATCH 32
#define BN_TOTAL (B_BATCH * N_NODES)   // 65536
#define EPS_BN 1e-5f
#define NEG_SLOPE 0.2f

typedef unsigned long long u64;

// ---------------- wave-level helpers (wave = 64 on gfx950) ----------------
__device__ __forceinline__ float wave_sum(float v) {
#pragma unroll
    for (int off = 32; off > 0; off >>= 1) v += __shfl_xor(v, off, 64);
    return v;
}
__device__ __forceinline__ float wave_max(float v) {
#pragma unroll
    for (int off = 32; off > 0; off >>= 1) v = fmaxf(v, __shfl_xor(v, off, 64));
    return v;
}

__device__ __forceinline__ u64 max64(u64 a, u64 b) { return a > b ? a : b; }
__device__ __forceinline__ u64 min64(u64 a, u64 b) { return a < b ? a : b; }

// Full bitonic sort (descending) of 64 u64 keys, one per lane.
__device__ __forceinline__ u64 bitonic_sort64_desc(u64 key, int lane) {
#pragma unroll
    for (int k = 2; k <= 64; k <<= 1) {
#pragma unroll
        for (int j = k >> 1; j >= 1; j >>= 1) {
            u64 pk = __shfl_xor(key, j, 64);
            bool dirDesc = ((lane & k) == 0);
            bool keepMax = (((lane & j) == 0) == dirDesc);
            key = keepMax ? max64(key, pk) : min64(key, pk);
        }
    }
    return key;
}

// Merge sorted-desc `a` (top-64 so far) with sorted-desc `b` (candidates),
// keeping the top-64, sorted desc.
__device__ __forceinline__ u64 bitonic_merge_top64(u64 a, u64 b, int lane) {
    u64 br = __shfl(b, 63 - lane, 64);   // reverse -> ascending
    u64 c = max64(a, br);                // top-64 of the 128, bitonic
#pragma unroll
    for (int j = 32; j >= 1; j >>= 1) {
        u64 pk = __shfl_xor(c, j, 64);
        bool keepMax = ((lane & j) == 0);
        c = keepMax ? max64(c, pk) : min64(c, pk);
    }
    return c;
}

// ---------------- K1: per-node precompute: norm, emb-half of e_src/e_dst ----
__global__ __launch_bounds__(64) void k_node_pre(
    const float* __restrict__ emb, const float* __restrict__ a_src,
    const float* __restrict__ a_dst, float* __restrict__ norms,
    float* __restrict__ es_emb, float* __restrict__ ed_emb) {
    int n = blockIdx.x;
    int d = threadIdx.x;
    float e = emb[n * D_EMB + d];
    float s2 = wave_sum(e * e);
    float es = wave_sum(e * a_src[D_EMB + d]);
    float ed = wave_sum(e * a_dst[D_EMB + d]);
    if (d == 0) {
        norms[n] = sqrtf(s2);
        es_emb[n] = es;
        ed_emb[n] = ed;
    }
}

// ---------------- K2: cosine rows + top-21 selection ------------------------
// Phase A: cooperative cos-row fill into LDS (4 rows/block, one per wave).
// Phase B: streaming threshold filter. Keys are u64 (monotonic(f32)<<32)|~j
// so key-order == (value desc, index asc) — exact jax.lax.top_k tie
// semantics. Per 64-chunk: ballot(key > t) appends candidates to an LDS
// buffer (t = current 21st key, only rises, provably admits every true
// top-21 member since keys are distinct). Buffer >= 64 -> one bitonic
// sort64 + merge into running sorted top-64, raise t. ~3 consolidations
// per row instead of round-2's 21 extract-max rounds x 672-element rescans.
__global__ __launch_bounds__(256) void k_topk(
    const float* __restrict__ emb, const float* __restrict__ norms,
    int* __restrict__ idxbuf) {
    __shared__ float cosrow[4][N_NODES];   // 32 KB
    __shared__ float embi[4][D_EMB];
    __shared__ float nI[4];
    __shared__ u64 candbuf[4][128];        // 4 KB

    int tid = threadIdx.x;
    int i0 = blockIdx.x * 4;

    {   // load the block's 4 emb rows + their norms
        int r = tid >> 6, d = tid & 63;
        embi[r][d] = emb[(i0 + r) * D_EMB + d];
        if (tid < 4) nI[tid] = norms[i0 + tid];
    }
    __syncthreads();

    // Phase A: fill 4 cos rows cooperatively
    for (int j = tid; j < N_NODES; j += 256) {
        const float4* ej = (const float4*)(emb + (size_t)j * D_EMB);
        float nj = norms[j];
        float dr0 = 0.f, dr1 = 0.f, dr2 = 0.f, dr3 = 0.f;
#pragma unroll
        for (int c = 0; c < 16; c++) {
            float4 v = ej[c];
            float4 w0 = ((const float4*)embi[0])[c];
            float4 w1 = ((const float4*)embi[1])[c];
            float4 w2 = ((const float4*)embi[2])[c];
            float4 w3 = ((const float4*)embi[3])[c];
            dr0 += v.x * w0.x + v.y * w0.y + v.z * w0.z + v.w * w0.w;
            dr1 += v.x * w1.x + v.y * w1.y + v.z * w1.z + v.w * w1.w;
            dr2 += v.x * w2.x + v.y * w2.y + v.z * w2.z + v.w * w2.w;
            dr3 += v.x * w3.x + v.y * w3.y + v.z * w3.z + v.w * w3.w;
        }
        cosrow[0][j] = dr0 / (nI[0] * nj);
        cosrow[1][j] = dr1 / (nI[1] * nj);
        cosrow[2][j] = dr2 / (nI[2] * nj);
        cosrow[3][j] = dr3 / (nI[3] * nj);
    }
    __syncthreads();

    // Phase B: per-wave streaming top-21
    int wid = tid >> 6, lane = tid & 63;
    int i = i0 + wid;
    u64* buf = candbuf[wid];

    u64 a = 0;      // running sorted-desc top-64 (lanes 0..20 = top-21)
    u64 t = 0;      // 21st key so far (wave-uniform); 0 == -inf sentinel
    int cnt = 0;    // candidate-buffer fill (wave-uniform)

#pragma unroll 1
    for (int c = 0; c < N_NODES / 64; c++) {
        int j = c * 64 + lane;
        unsigned u = __float_as_uint(cosrow[wid][j]);
        u = (u & 0x80000000u) ? ~u : (u | 0x80000000u);  // monotonic f32->u32
        u64 key = ((u64)u << 32) | (unsigned)(~j);
        unsigned long long ball = __ballot(key > t);
        if (ball) {
            int ofs = __popcll(ball & ((1ull << lane) - 1ull));
            if (key > t) buf[cnt + ofs] = key;
            cnt += (int)__popcll(ball);
            if (cnt >= 64) {  // consolidate (wave-uniform branch)
                u64 nk = (lane < 64) ? buf[lane] : 0;  // take = 64 (cnt<=127)
                nk = bitonic_sort64_desc(nk, lane);
                a = bitonic_merge_top64(a, nk, lane);
                t = __shfl(a, 20, 64);
                int rem = cnt - 64;
                u64 mv = (lane < rem) ? buf[64 + lane] : 0;
                if (lane < rem) buf[lane] = mv;
                cnt = rem;
            }
        }
    }
    // final flush (cnt <= 127 -> at most 2 iterations)
    while (cnt > 0) {
        int take = cnt < 64 ? cnt : 64;
        u64 nk = (lane < take) ? buf[lane] : 0;
        nk = bitonic_sort64_desc(nk, lane);
        a = bitonic_merge_top64(a, nk, lane);
        t = __shfl(a, 20, 64);
        int rem = cnt - take;
        u64 mv = (lane < rem) ? buf[take + lane] : 0;
        if (lane < rem) buf[lane] = mv;
        cnt = rem;
    }

    if (lane < TOPK) {
        unsigned low = (unsigned)a;            // == ~j
        idxbuf[i * TOPK + lane] = (int)(~low);
    }
}

// ---------------- K3: h = x@W^T + Wb ; e_src/e_dst --------------------------
__global__ __launch_bounds__(256) void k_h(
    const float* __restrict__ x, const float* __restrict__ W,
    const float* __restrict__ Wb, const float* __restrict__ a_src,
    const float* __restrict__ a_dst, const float* __restrict__ es_emb,
    const float* __restrict__ ed_emb, float* __restrict__ h,
    float* __restrict__ e_src, float* __restrict__ e_dst) {
    int wid = threadIdx.x >> 6, lane = threadIdx.x & 63;
    int node = blockIdx.x * 4 + wid;          // node = b*N + n
    int n = node & (N_NODES - 1);
    const float* xp = x + (size_t)node * T_WIN;
    float x0 = xp[0], x1 = xp[1], x2 = xp[2], x3 = xp[3], x4 = xp[4];
    const float* wp = W + lane * T_WIN;       // W is [D,T] row-major
    float hv = Wb[lane] + x0 * wp[0] + x1 * wp[1] + x2 * wp[2] + x3 * wp[3] + x4 * wp[4];
    h[(size_t)node * D_EMB + lane] = hv;
    float es = wave_sum(hv * a_src[lane]);
    float ed = wave_sum(hv * a_dst[lane]);
    if (lane == 0) {
        e_src[node] = es + es_emb[n];
        e_dst[node] = ed + ed_emb[n];
    }
}

// ---------------- K4: attention message passing + pre-BN output + stats -----
__global__ __launch_bounds__(256) void k_msg(
    const int* __restrict__ idxbuf, const float* __restrict__ e_src,
    const float* __restrict__ e_dst, const float* __restrict__ h,
    const float* __restrict__ emb, float* __restrict__ obuf,
    float* __restrict__ stats, float* __restrict__ stats2) {
    int wid = threadIdx.x >> 6, lane = threadIdx.x & 63;
    int gw = blockIdx.x * 4 + wid;
    int stride = gridDim.x * 4;
    float acc = 0.f, acc2 = 0.f;

    for (int node = gw; node < BN_TOTAL; node += stride) {
        int b = node >> 11;                   // node / N
        int i = node & (N_NODES - 1);
        // lane k<21 handles neighbor k
        int jk = idxbuf[i * TOPK + (lane < TOPK ? lane : 0)];
        float ev = e_src[node] + e_dst[b * N_NODES + jk];
        ev = ev > 0.f ? ev : NEG_SLOPE * ev;  // leaky_relu
        float evm = (lane < TOPK) ? ev : -3e38f;
        float m = wave_max(evm);
        float w = (lane < TOPK) ? __expf(ev - m) : 0.f;
        float s = wave_sum(w);
        float alpha = w / s;

        const float* hb = h + (size_t)b * N_NODES * D_EMB;
        float z = 0.f;
#pragma unroll
        for (int k = 0; k < TOPK; k++) {
            float a = __shfl(alpha, k, 64);
            int j = __shfl(jk, k, 64);
            z += a * hb[(size_t)j * D_EMB + lane];
        }
        float o = fmaxf(z, 0.f) * emb[i * D_EMB + lane];
        obuf[(size_t)node * D_EMB + lane] = o;
        acc += o;
        acc2 += o * o;
    }

    // block-level channel partials -> one atomic per channel per block
    __shared__ float sa[4][D_EMB], sb[4][D_EMB];
    sa[wid][lane] = acc;
    sb[wid][lane] = acc2;
    __syncthreads();
    if (wid == 0) {
        float t = sa[0][lane] + sa[1][lane] + sa[2][lane] + sa[3][lane];
        float t2 = sb[0][lane] + sb[1][lane] + sb[2][lane] + sb[3][lane];
        atomicAdd(&stats[lane], t);
        atomicAdd(&stats2[lane], t2);
    }
}

// ---------------- K5: BN apply + relu + fc ---------------------------------
__global__ __launch_bounds__(256) void k_out(
    const float* __restrict__ obuf, const float* __restrict__ stats,
    const float* __restrict__ stats2, const float* __restrict__ gamma,
    const float* __restrict__ beta, const float* __restrict__ fc_w,
    const float* __restrict__ fc_b, float* __restrict__ out) {
    int wid = threadIdx.x >> 6, lane = threadIdx.x & 63;
    int node = blockIdx.x * 4 + wid;
    const float invM = 1.0f / (float)BN_TOTAL;
    float mean = stats[lane] * invM;
    float var = stats2[lane] * invM - mean * mean;
    float inv = rsqrtf(var + EPS_BN);
    float o = obuf[(size_t)node * D_EMB + lane];
    float v = (o - mean) * inv * gamma[lane] + beta[lane];
    v = fmaxf(v, 0.f);
    float p = wave_sum(v * fc_w[lane]);
    if (lane == 0) out[node] = p + fc_b[0];
}

// ---------------- launch ----------------------------------------------------
extern "C" void kernel_launch(void* const* d_in, const int* in_sizes, int n_in,
                              void* d_out, int out_size, void* d_ws, size_t ws_size,
                              hipStream_t stream) {
    const float* x     = (const float*)d_in[0];   // [B,N,T]
    const float* emb   = (const float*)d_in[1];   // [N,D]
    const float* W     = (const float*)d_in[2];   // [D,T]
    const float* Wb    = (const float*)d_in[3];   // [D]
    const float* a_src = (const float*)d_in[4];   // [2D]
    const float* a_dst = (const float*)d_in[5];   // [2D]
    const float* gamma = (const float*)d_in[6];   // [D]
    const float* beta  = (const float*)d_in[7];   // [D]
    const float* fc_w  = (const float*)d_in[8];   // [1,D]
    const float* fc_b  = (const float*)d_in[9];   // [1]
    float* out = (float*)d_out;                   // [B,N]

    char* ws = (char*)d_ws;
    // workspace layout (256B-aligned chunks)
    float* stats  = (float*)(ws + 0);             // 64 f
    float* stats2 = (float*)(ws + 256);           // 64 f
    int*   idxbuf = (int*)  (ws + 512);           // N*21 ints  = 172032 B
    float* norms  = (float*)(ws + 172544);        // N f
    float* es_emb = (float*)(ws + 180736);        // N f
    float* ed_emb = (float*)(ws + 188928);        // N f
    float* e_src  = (float*)(ws + 197120);        // B*N f
    float* e_dst  = (float*)(ws + 459264);        // B*N f
    float* h      = (float*)(ws + 721408);        // B*N*D f = 16 MB
    float* obuf   = (float*)(ws + 17498624);      // B*N*D f = 16 MB
    // total: 34,275,840 bytes

    hipMemsetAsync(stats, 0, 2 * 256, stream);    // zero stats+stats2

    k_node_pre<<<N_NODES, 64, 0, stream>>>(emb, a_src, a_dst, norms, es_emb, ed_emb);
    k_topk<<<N_NODES / 4, 256, 0, stream>>>(emb, norms, idxbuf);
    k_h<<<BN_TOTAL / 4, 256, 0, stream>>>(x, W, Wb, a_src, a_dst, es_emb, ed_emb,
                                          h, e_src, e_dst);
    k_msg<<<2048, 256, 0, stream>>>(idxbuf, e_src, e_dst, h, emb, obuf, stats, stats2);
    k_out<<<BN_TOTAL / 4, 256, 0, stream>>>(obuf, stats, stats2, gamma, beta,
                                            fc_w, fc_b, out);
}

// Round 4
// 215.183 us; speedup vs baseline: 1.3675x; 1.0527x over previous
//
#include <hip/hip_runtime.h>
#include <math.h>

#define N_NODES 2048
#define T_WIN 5
#define D_EMB 64
#define TOPK 21
#define B_BATCH 32
#define BN_TOTAL (B_BATCH * N_NODES)   // 65536
#define EPS_BN 1e-5f
#define NEG_SLOPE 0.2f
#define STATS_STRIDE 16                // pad stats to 64 B/channel: atomics spread over 64 lines

typedef unsigned long long u64;

// ---------------- wave-level helpers (wave = 64 on gfx950) ----------------
__device__ __forceinline__ float wave_sum(float v) {
#pragma unroll
    for (int off = 32; off > 0; off >>= 1) v += __shfl_xor(v, off, 64);
    return v;
}

__device__ __forceinline__ u64 max64(u64 a, u64 b) { return a > b ? a : b; }
__device__ __forceinline__ u64 min64(u64 a, u64 b) { return a < b ? a : b; }

__device__ __forceinline__ u64 bitonic_sort64_desc(u64 key, int lane) {
#pragma unroll
    for (int k = 2; k <= 64; k <<= 1) {
#pragma unroll
        for (int j = k >> 1; j >= 1; j >>= 1) {
            u64 pk = __shfl_xor(key, j, 64);
            bool dirDesc = ((lane & k) == 0);
            bool keepMax = (((lane & j) == 0) == dirDesc);
            key = keepMax ? max64(key, pk) : min64(key, pk);
        }
    }
    return key;
}

__device__ __forceinline__ u64 bitonic_merge_top64(u64 a, u64 b, int lane) {
    u64 br = __shfl(b, 63 - lane, 64);
    u64 c = max64(a, br);
#pragma unroll
    for (int j = 32; j >= 1; j >>= 1) {
        u64 pk = __shfl_xor(c, j, 64);
        bool keepMax = ((lane & j) == 0);
        c = keepMax ? max64(c, pk) : min64(c, pk);
    }
    return c;
}

// ---------------- K1: per-node norms (bit-identical to prior rounds) --------
__global__ __launch_bounds__(64) void k_node_pre(
    const float* __restrict__ emb, float* __restrict__ norms) {
    int n = blockIdx.x;
    int d = threadIdx.x;
    float e = emb[n * D_EMB + d];
    float s2 = wave_sum(e * e);
    if (d == 0) norms[n] = sqrtf(s2);
}

// ---------------- K2: cosine rows + top-21 selection ------------------------
// Phase A v2: the 4 query rows are WAVE-UNIFORM -> read them from global as
// uniform scalars (s_load + SGPR operand in v_fma), eliminating the 512
// ds_read_b128/thread of rounds 1-3. Dot expression kept verbatim ->
// bit-identical cos -> identical top-k sets (the only discrete/fragile path).
// Phase B: streaming threshold filter + bitonic consolidation (round 3).
__global__ __launch_bounds__(256) void k_topk(
    const float* __restrict__ emb, const float* __restrict__ norms,
    int* __restrict__ idxbuf) {
    __shared__ float cosrow[4][N_NODES];   // 32 KB
    __shared__ u64 candbuf[4][128];        // 4 KB

    int tid = threadIdx.x;
    int i0 = blockIdx.x * 4;

    const float n0 = norms[i0], n1 = norms[i0 + 1];
    const float n2 = norms[i0 + 2], n3 = norms[i0 + 3];
    const float4* W0 = (const float4*)(emb + (size_t)(i0 + 0) * D_EMB);
    const float4* W1 = (const float4*)(emb + (size_t)(i0 + 1) * D_EMB);
    const float4* W2 = (const float4*)(emb + (size_t)(i0 + 2) * D_EMB);
    const float4* W3 = (const float4*)(emb + (size_t)(i0 + 3) * D_EMB);

    for (int j = tid; j < N_NODES; j += 256) {
        const float4* ej = (const float4*)(emb + (size_t)j * D_EMB);
        float nj = norms[j];
        float dr0 = 0.f, dr1 = 0.f, dr2 = 0.f, dr3 = 0.f;
#pragma unroll
        for (int c = 0; c < 16; c++) {
            float4 v = ej[c];
            float4 w0 = W0[c];   // uniform address -> scalar load
            float4 w1 = W1[c];
            float4 w2 = W2[c];
            float4 w3 = W3[c];
            dr0 += v.x * w0.x + v.y * w0.y + v.z * w0.z + v.w * w0.w;
            dr1 += v.x * w1.x + v.y * w1.y + v.z * w1.z + v.w * w1.w;
            dr2 += v.x * w2.x + v.y * w2.y + v.z * w2.z + v.w * w2.w;
            dr3 += v.x * w3.x + v.y * w3.y + v.z * w3.z + v.w * w3.w;
        }
        cosrow[0][j] = dr0 / (n0 * nj);
        cosrow[1][j] = dr1 / (n1 * nj);
        cosrow[2][j] = dr2 / (n2 * nj);
        cosrow[3][j] = dr3 / (n3 * nj);
    }
    __syncthreads();

    // Phase B: per-wave streaming top-21
    int wid = tid >> 6, lane = tid & 63;
    int i = i0 + wid;
    u64* buf = candbuf[wid];

    u64 a = 0;      // running sorted-desc top-64 (lanes 0..20 = top-21)
    u64 t = 0;      // 21st key so far (wave-uniform); 0 == -inf
    int cnt = 0;

#pragma unroll 1
    for (int c = 0; c < N_NODES / 64; c++) {
        int j = c * 64 + lane;
        unsigned u = __float_as_uint(cosrow[wid][j]);
        u = (u & 0x80000000u) ? ~u : (u | 0x80000000u);  // monotonic f32->u32
        u64 key = ((u64)u << 32) | (unsigned)(~j);
        unsigned long long ball = __ballot(key > t);
        if (ball) {
            int ofs = __popcll(ball & ((1ull << lane) - 1ull));
            if (key > t) buf[cnt + ofs] = key;
            cnt += (int)__popcll(ball);
            if (cnt >= 64) {
                u64 nk = buf[lane];
                nk = bitonic_sort64_desc(nk, lane);
                a = bitonic_merge_top64(a, nk, lane);
                t = __shfl(a, 20, 64);
                int rem = cnt - 64;
                u64 mv = (lane < rem) ? buf[64 + lane] : 0;
                if (lane < rem) buf[lane] = mv;
                cnt = rem;
            }
        }
    }
    while (cnt > 0) {
        int take = cnt < 64 ? cnt : 64;
        u64 nk = (lane < take) ? buf[lane] : 0;
        nk = bitonic_sort64_desc(nk, lane);
        a = bitonic_merge_top64(a, nk, lane);
        t = __shfl(a, 20, 64);
        int rem = cnt - take;
        u64 mv = (lane < rem) ? buf[take + lane] : 0;
        if (lane < rem) buf[lane] = mv;
        cnt = rem;
    }

    if (lane < TOPK) {
        idxbuf[i * TOPK + lane] = (int)(~(unsigned)a);
    }
}

// ---------------- K3: h2[N][B][D] = x@W^T + Wb ; es2/ed2 [N][B] -------------
// emb-half of e_src/e_dst folded in (smooth path; order change safe).
__global__ __launch_bounds__(256) void k_h(
    const float* __restrict__ x, const float* __restrict__ W,
    const float* __restrict__ Wb, const float* __restrict__ a_src,
    const float* __restrict__ a_dst, const float* __restrict__ emb,
    float* __restrict__ h2, float* __restrict__ es2, float* __restrict__ ed2) {
    int wid = threadIdx.x >> 6, lane = threadIdx.x & 63;
    int gw = blockIdx.x * 4 + wid;
    const float* wp = W + lane * T_WIN;       // W is [D,T] row-major
    float w0 = wp[0], w1 = wp[1], w2 = wp[2], w3 = wp[3], w4 = wp[4];
    float bias = Wb[lane];
    float as = a_src[lane], asE = a_src[D_EMB + lane];
    float ad = a_dst[lane], adE = a_dst[D_EMB + lane];

    for (int node = gw; node < BN_TOTAL; node += 8192) {
        int b = node >> 11;                   // node / N
        int n = node & (N_NODES - 1);
        const float* xp = x + (size_t)node * T_WIN;
        float hv = bias + xp[0] * w0 + xp[1] * w1 + xp[2] * w2 + xp[3] * w3 + xp[4] * w4;
        float e = emb[n * D_EMB + lane];
        h2[(size_t)n * (B_BATCH * D_EMB) + b * D_EMB + lane] = hv;
        float es = wave_sum(hv * as + e * asE);
        float ed = wave_sum(hv * ad + e * adE);
        if (lane == 0) {
            es2[n * B_BATCH + b] = es;
            ed2[n * B_BATCH + b] = ed;
        }
    }
}

// ---------------- K4: message passing, one block per node i -----------------
// threads: t = b*8 + s  (b in [0,32), s in [0,8));  lane order means per-k
// gather h2[j][b][s*8..] is 8 KB perfectly contiguous across the block.
__global__ __launch_bounds__(256) void k_msg(
    const int* __restrict__ idxbuf, const float* __restrict__ es2,
    const float* __restrict__ ed2, const float* __restrict__ h2,
    const float* __restrict__ emb, float* __restrict__ obuf,
    float* __restrict__ stats, float* __restrict__ stats2) {
    int i = blockIdx.x;
    int t = threadIdx.x;
    int b = t >> 3, s = t & 7;

    __shared__ int sj[TOPK];
    __shared__ float semb[D_EMB];
    __shared__ float salpha[B_BATCH][TOPK];   // stride 21: banks distinct for b=0..7
    __shared__ float red1[4][8][8], red2[4][8][8];

    if (t < TOPK) sj[t] = idxbuf[i * TOPK + t];
    if (t >= 64 && t < 64 + D_EMB) semb[t - 64] = emb[i * D_EMB + (t - 64)];
    __syncthreads();

    // ---- softmax over the 21 neighbors, per b (8-lane shuffle groups) ----
    float es_i = es2[i * B_BATCH + b];
    float e0 = es_i + ed2[sj[s] * B_BATCH + b];
    float e1 = es_i + ed2[sj[s + 8] * B_BATCH + b];
    float ev0 = e0 > 0.f ? e0 : NEG_SLOPE * e0;
    float ev1 = e1 > 0.f ? e1 : NEG_SLOPE * e1;
    float ev2 = -3e38f;
    if (s < 5) {
        float e2 = es_i + ed2[sj[s + 16] * B_BATCH + b];
        ev2 = e2 > 0.f ? e2 : NEG_SLOPE * e2;
    }
    float m = fmaxf(fmaxf(ev0, ev1), ev2);
#pragma unroll
    for (int off = 1; off <= 4; off <<= 1) m = fmaxf(m, __shfl_xor(m, off, 64));
    float a0 = __expf(ev0 - m), a1 = __expf(ev1 - m);
    float a2 = (s < 5) ? __expf(ev2 - m) : 0.f;
    float ssum = a0 + a1 + a2;
#pragma unroll
    for (int off = 1; off <= 4; off <<= 1) ssum += __shfl_xor(ssum, off, 64);
    float inv = 1.0f / ssum;
    salpha[b][s] = a0 * inv;
    salpha[b][s + 8] = a1 * inv;
    if (s < 5) salpha[b][s + 16] = a2 * inv;
    __syncthreads();

    // ---- gather: z[b][s*8 .. s*8+7] ----
    const float4* hp = (const float4*)h2;
    int base = b * 16 + s * 2;                // float4 units within a j-row
    float4 z0 = make_float4(0.f, 0.f, 0.f, 0.f);
    float4 z1 = make_float4(0.f, 0.f, 0.f, 0.f);
#pragma unroll
    for (int k = 0; k < TOPK; k++) {
        float a = salpha[b][k];
        const float4* p = hp + ((size_t)sj[k] * (B_BATCH * D_EMB / 4) + base);
        float4 v0 = p[0], v1 = p[1];
        z0.x = fmaf(a, v0.x, z0.x); z0.y = fmaf(a, v0.y, z0.y);
        z0.z = fmaf(a, v0.z, z0.z); z0.w = fmaf(a, v0.w, z0.w);
        z1.x = fmaf(a, v1.x, z1.x); z1.y = fmaf(a, v1.y, z1.y);
        z1.z = fmaf(a, v1.z, z1.z); z1.w = fmaf(a, v1.w, z1.w);
    }
    float4 m0 = ((const float4*)semb)[s * 2];
    float4 m1 = ((const float4*)semb)[s * 2 + 1];
    float4 o0, o1;
    o0.x = fmaxf(z0.x, 0.f) * m0.x; o0.y = fmaxf(z0.y, 0.f) * m0.y;
    o0.z = fmaxf(z0.z, 0.f) * m0.z; o0.w = fmaxf(z0.w, 0.f) * m0.w;
    o1.x = fmaxf(z1.x, 0.f) * m1.x; o1.y = fmaxf(z1.y, 0.f) * m1.y;
    o1.z = fmaxf(z1.z, 0.f) * m1.z; o1.w = fmaxf(z1.w, 0.f) * m1.w;

    ((float4*)obuf)[((size_t)b * N_NODES + i) * 16 + s * 2] = o0;
    ((float4*)obuf)[((size_t)b * N_NODES + i) * 16 + s * 2 + 1] = o1;

    // ---- BN stats partials: per-channel sums over b ----
    float4 q0, q1;
    q0.x = o0.x * o0.x; q0.y = o0.y * o0.y; q0.z = o0.z * o0.z; q0.w = o0.w * o0.w;
    q1.x = o1.x * o1.x; q1.y = o1.y * o1.y; q1.z = o1.z * o1.z; q1.w = o1.w * o1.w;
#pragma unroll
    for (int off = 8; off <= 32; off <<= 1) {
        o0.x += __shfl_xor(o0.x, off, 64); o0.y += __shfl_xor(o0.y, off, 64);
        o0.z += __shfl_xor(o0.z, off, 64); o0.w += __shfl_xor(o0.w, off, 64);
        o1.x += __shfl_xor(o1.x, off, 64); o1.y += __shfl_xor(o1.y, off, 64);
        o1.z += __shfl_xor(o1.z, off, 64); o1.w += __shfl_xor(o1.w, off, 64);
        q0.x += __shfl_xor(q0.x, off, 64); q0.y += __shfl_xor(q0.y, off, 64);
        q0.z += __shfl_xor(q0.z, off, 64); q0.w += __shfl_xor(q0.w, off, 64);
        q1.x += __shfl_xor(q1.x, off, 64); q1.y += __shfl_xor(q1.y, off, 64);
        q1.z += __shfl_xor(q1.z, off, 64); q1.w += __shfl_xor(q1.w, off, 64);
    }
    int lane = t & 63, w = t >> 6;
    if (lane < 8) {   // lane == s, b == 8w
        ((float4*)&red1[w][lane][0])[0] = o0; ((float4*)&red1[w][lane][0])[1] = o1;
        ((float4*)&red2[w][lane][0])[0] = q0; ((float4*)&red2[w][lane][0])[1] = q1;
    }
    __syncthreads();
    if (t < D_EMB) {
        int ss = t >> 3, qq = t & 7;
        float su = red1[0][ss][qq] + red1[1][ss][qq] + red1[2][ss][qq] + red1[3][ss][qq];
        float sq = red2[0][ss][qq] + red2[1][ss][qq] + red2[2][ss][qq] + red2[3][ss][qq];
        atomicAdd(&stats[t * STATS_STRIDE], su);
        atomicAdd(&stats2[t * STATS_STRIDE], sq);
    }
}

// ---------------- K5: BN apply + relu + fc ---------------------------------
__global__ __launch_bounds__(256) void k_out(
    const float* __restrict__ obuf, const float* __restrict__ stats,
    const float* __restrict__ stats2, const float* __restrict__ gamma,
    const float* __restrict__ beta, const float* __restrict__ fc_w,
    const float* __restrict__ fc_b, float* __restrict__ out) {
    int wid = threadIdx.x >> 6, lane = threadIdx.x & 63;
    int gw = blockIdx.x * 4 + wid;
    const float invM = 1.0f / (float)BN_TOTAL;
    float mean = stats[lane * STATS_STRIDE] * invM;
    float var = stats2[lane * STATS_STRIDE] * invM - mean * mean;
    float inv = rsqrtf(var + EPS_BN);
    float g = gamma[lane], bt = beta[lane], fw = fc_w[lane], fb = fc_b[0];
    for (int node = gw; node < BN_TOTAL; node += 8192) {
        float o = obuf[(size_t)node * D_EMB + lane];
        float v = (o - mean) * inv * g + bt;
        v = fmaxf(v, 0.f);
        float p = wave_sum(v * fw);
        if (lane == 0) out[node] = p + fb;
    }
}

// ---------------- launch ----------------------------------------------------
extern "C" void kernel_launch(void* const* d_in, const int* in_sizes, int n_in,
                              void* d_out, int out_size, void* d_ws, size_t ws_size,
                              hipStream_t stream) {
    const float* x     = (const float*)d_in[0];   // [B,N,T]
    const float* emb   = (const float*)d_in[1];   // [N,D]
    const float* W     = (const float*)d_in[2];   // [D,T]
    const float* Wb    = (const float*)d_in[3];   // [D]
    const float* a_src = (const float*)d_in[4];   // [2D]
    const float* a_dst = (const float*)d_in[5];   // [2D]
    const float* gamma = (const float*)d_in[6];   // [D]
    const float* beta  = (const float*)d_in[7];   // [D]
    const float* fc_w  = (const float*)d_in[8];   // [1,D]
    const float* fc_b  = (const float*)d_in[9];   // [1]
    float* out = (float*)d_out;                   // [B,N]

    char* ws = (char*)d_ws;
    float* stats  = (float*)(ws + 0);             // 64*16 f = 4 KB
    float* stats2 = (float*)(ws + 4096);          // 4 KB
    int*   idxbuf = (int*)  (ws + 8192);          // N*21 ints = 172032 B
    float* norms  = (float*)(ws + 180224);        // N f
    float* es2    = (float*)(ws + 188416);        // N*B f = 256 KB, [N][B]
    float* ed2    = (float*)(ws + 450560);        // 256 KB, [N][B]
    float* h2     = (float*)(ws + 712704);        // N*B*D f = 16 MB, [N][B][D]
    float* obuf   = (float*)(ws + 17489920);      // 16 MB, [B][N][D]
    // total: 34,267,136 bytes

    hipMemsetAsync(stats, 0, 8192, stream);

    k_node_pre<<<N_NODES, 64, 0, stream>>>(emb, norms);
    k_topk<<<N_NODES / 4, 256, 0, stream>>>(emb, norms, idxbuf);
    k_h<<<2048, 256, 0, stream>>>(x, W, Wb, a_src, a_dst, emb, h2, es2, ed2);
    k_msg<<<N_NODES, 256, 0, stream>>>(idxbuf, es2, ed2, h2, emb, obuf, stats, stats2);
    k_out<<<2048, 256, 0, stream>>>(obuf, stats, stats2, gamma, beta, fc_w, fc_b, out);
}

// Round 5
// 206.691 us; speedup vs baseline: 1.4237x; 1.0411x over previous
//
#include <hip/hip_runtime.h>
#include <math.h>

#define N_NODES 2048
#define T_WIN 5
#define D_EMB 64
#define TOPK 21
#define B_BATCH 32
#define BN_TOTAL (B_BATCH * N_NODES)   // 65536
#define EPS_BN 1e-5f
#define NEG_SLOPE 0.2f
#define STATS_STRIDE 16

typedef unsigned long long u64;

// ---------------- wave-level helpers (wave = 64 on gfx950) ----------------
__device__ __forceinline__ float wave_sum(float v) {
#pragma unroll
    for (int off = 32; off > 0; off >>= 1) v += __shfl_xor(v, off, 64);
    return v;
}
__device__ __forceinline__ float wave_max(float v) {
#pragma unroll
    for (int off = 32; off > 0; off >>= 1) v = fmaxf(v, __shfl_xor(v, off, 64));
    return v;
}

__device__ __forceinline__ u64 max64(u64 a, u64 b) { return a > b ? a : b; }
__device__ __forceinline__ u64 min64(u64 a, u64 b) { return a < b ? a : b; }

__device__ __forceinline__ u64 bitonic_sort64_desc(u64 key, int lane) {
#pragma unroll
    for (int k = 2; k <= 64; k <<= 1) {
#pragma unroll
        for (int j = k >> 1; j >= 1; j >>= 1) {
            u64 pk = __shfl_xor(key, j, 64);
            bool dirDesc = ((lane & k) == 0);
            bool keepMax = (((lane & j) == 0) == dirDesc);
            key = keepMax ? max64(key, pk) : min64(key, pk);
        }
    }
    return key;
}

__device__ __forceinline__ u64 bitonic_merge_top64(u64 a, u64 b, int lane) {
    u64 br = __shfl(b, 63 - lane, 64);
    u64 c = max64(a, br);
#pragma unroll
    for (int j = 32; j >= 1; j >>= 1) {
        u64 pk = __shfl_xor(c, j, 64);
        bool keepMax = ((lane & j) == 0);
        c = keepMax ? max64(c, pk) : min64(c, pk);
    }
    return c;
}

// ---------------- K1: per-node norms ---------------------------------------
__global__ __launch_bounds__(64) void k_node_pre(
    const float* __restrict__ emb, float* __restrict__ norms) {
    int n = blockIdx.x;
    int d = threadIdx.x;
    float e = emb[n * D_EMB + d];
    float s2 = wave_sum(e * e);
    if (d == 0) norms[n] = sqrtf(s2);
}

// ---------------- K2a: Gram/cos matrix, tiled GEMM --------------------------
// 64x64 C-tile per block; A/B tiles staged coalesced into LDS stored d-major
// [64][68] (pad 68 -> <=2-way bank conflicts = free); 4x4 register tile:
// 16 fma per 2 ds_read_b128. Replaces the old Phase A whose ej loads put
// adjacent lanes 256 B apart (64 cache lines per load instruction).
__global__ __launch_bounds__(256) void k_gram(
    const float* __restrict__ emb, const float* __restrict__ norms,
    float* __restrict__ cosM) {
    __shared__ __align__(16) float As[64][68];   // [d][i]
    __shared__ __align__(16) float Bs[64][68];   // [d][j]
    int t = threadIdx.x;
    int bi = blockIdx.x & 31, bj = blockIdx.x >> 5;
    int i0 = bi * 64, j0 = bj * 64;

    {   // coalesced stage: lanes 0-3 cover 64 contiguous bytes of one row
        int r = t >> 2, c0 = t & 3;
        const float4* srcA = (const float4*)(emb + (size_t)(i0 + r) * D_EMB);
        const float4* srcB = (const float4*)(emb + (size_t)(j0 + r) * D_EMB);
#pragma unroll
        for (int k = 0; k < 4; k++) {
            int f4 = c0 + 4 * k;
            float4 v = srcA[f4];
            int d = 4 * f4;
            As[d][r] = v.x; As[d + 1][r] = v.y; As[d + 2][r] = v.z; As[d + 3][r] = v.w;
            float4 w = srcB[f4];
            Bs[d][r] = w.x; Bs[d + 1][r] = w.y; Bs[d + 2][r] = w.z; Bs[d + 3][r] = w.w;
        }
    }
    __syncthreads();

    int ti = t & 15, tj = t >> 4;
    float acc[4][4] = {};
#pragma unroll
    for (int d = 0; d < 64; d++) {
        float4 a = *(const float4*)&As[d][4 * ti];
        float4 b = *(const float4*)&Bs[d][4 * tj];
        acc[0][0] += a.x * b.x; acc[0][1] += a.x * b.y; acc[0][2] += a.x * b.z; acc[0][3] += a.x * b.w;
        acc[1][0] += a.y * b.x; acc[1][1] += a.y * b.y; acc[1][2] += a.y * b.z; acc[1][3] += a.y * b.w;
        acc[2][0] += a.z * b.x; acc[2][1] += a.z * b.y; acc[2][2] += a.z * b.z; acc[2][3] += a.z * b.w;
        acc[3][0] += a.w * b.x; acc[3][1] += a.w * b.y; acc[3][2] += a.w * b.z; acc[3][3] += a.w * b.w;
    }

    float ni0 = norms[i0 + 4 * ti], ni1 = norms[i0 + 4 * ti + 1];
    float ni2 = norms[i0 + 4 * ti + 2], ni3 = norms[i0 + 4 * ti + 3];
    float nj0 = norms[j0 + 4 * tj], nj1 = norms[j0 + 4 * tj + 1];
    float nj2 = norms[j0 + 4 * tj + 2], nj3 = norms[j0 + 4 * tj + 3];
    float nis[4] = {ni0, ni1, ni2, ni3};
    float njs[4] = {nj0, nj1, nj2, nj3};
#pragma unroll
    for (int r = 0; r < 4; r++) {
        float4 o;
        o.x = acc[r][0] / (nis[r] * njs[0]);
        o.y = acc[r][1] / (nis[r] * njs[1]);
        o.z = acc[r][2] / (nis[r] * njs[2]);
        o.w = acc[r][3] / (nis[r] * njs[3]);
        *(float4*)(cosM + (size_t)(i0 + 4 * ti + r) * N_NODES + j0 + 4 * tj) = o;
    }
}

// ---------------- K2b: top-21 selection (streaming filter from global) ------
// Keys u64 (monotonic(f32)<<32)|~j: order == (value desc, index asc) — exact
// jax.lax.top_k tie semantics. Coalesced row reads; tiny LDS -> high occupancy.
__global__ __launch_bounds__(256) void k_select(
    const float* __restrict__ cosM, int* __restrict__ idxbuf) {
    __shared__ u64 candbuf[4][128];
    int tid = threadIdx.x;
    int wid = tid >> 6, lane = tid & 63;
    int i = blockIdx.x * 4 + wid;
    const float* row = cosM + (size_t)i * N_NODES;
    u64* buf = candbuf[wid];

    u64 a = 0;
    u64 t = 0;
    int cnt = 0;

#pragma unroll 1
    for (int c = 0; c < N_NODES / 64; c++) {
        int j = c * 64 + lane;
        unsigned u = __float_as_uint(row[j]);
        u = (u & 0x80000000u) ? ~u : (u | 0x80000000u);
        u64 key = ((u64)u << 32) | (unsigned)(~j);
        unsigned long long ball = __ballot(key > t);
        if (ball) {
            int ofs = __popcll(ball & ((1ull << lane) - 1ull));
            if (key > t) buf[cnt + ofs] = key;
            cnt += (int)__popcll(ball);
            if (cnt >= 64) {
                u64 nk = buf[lane];
                nk = bitonic_sort64_desc(nk, lane);
                a = bitonic_merge_top64(a, nk, lane);
                t = __shfl(a, 20, 64);
                int rem = cnt - 64;
                u64 mv = (lane < rem) ? buf[64 + lane] : 0;
                if (lane < rem) buf[lane] = mv;
                cnt = rem;
            }
        }
    }
    while (cnt > 0) {
        int take = cnt < 64 ? cnt : 64;
        u64 nk = (lane < take) ? buf[lane] : 0;
        nk = bitonic_sort64_desc(nk, lane);
        a = bitonic_merge_top64(a, nk, lane);
        t = __shfl(a, 20, 64);
        int rem = cnt - take;
        u64 mv = (lane < rem) ? buf[take + lane] : 0;
        if (lane < rem) buf[lane] = mv;
        cnt = rem;
    }

    if (lane < TOPK) idxbuf[i * TOPK + lane] = (int)(~(unsigned)a);
}

// ---------------- K3: h[B][N][D] = x@W^T + Wb ; es2/ed2 [N][B] --------------
__global__ __launch_bounds__(256) void k_h(
    const float* __restrict__ x, const float* __restrict__ W,
    const float* __restrict__ Wb, const float* __restrict__ a_src,
    const float* __restrict__ a_dst, const float* __restrict__ emb,
    float* __restrict__ h, float* __restrict__ es2, float* __restrict__ ed2) {
    int wid = threadIdx.x >> 6, lane = threadIdx.x & 63;
    int gw = blockIdx.x * 4 + wid;
    const float* wp = W + lane * T_WIN;
    float w0 = wp[0], w1 = wp[1], w2 = wp[2], w3 = wp[3], w4 = wp[4];
    float bias = Wb[lane];
    float as = a_src[lane], asE = a_src[D_EMB + lane];
    float ad = a_dst[lane], adE = a_dst[D_EMB + lane];

    for (int node = gw; node < BN_TOTAL; node += 8192) {
        int b = node >> 11;
        int n = node & (N_NODES - 1);
        const float* xp = x + (size_t)node * T_WIN;
        float hv = bias + xp[0] * w0 + xp[1] * w1 + xp[2] * w2 + xp[3] * w3 + xp[4] * w4;
        float e = emb[n * D_EMB + lane];
        h[(size_t)node * D_EMB + lane] = hv;     // [B][N][D] (node is b-major)
        float es = wave_sum(hv * as + e * asE);
        float ed = wave_sum(hv * ad + e * adE);
        if (lane == 0) {
            es2[n * B_BATCH + b] = es;
            ed2[n * B_BATCH + b] = ed;
        }
    }
}

// ---------------- K4: message passing, XCD-local batches ---------------------
// Block g -> batch b = (g&7) + 8*((g>>3)&3): XCD = g%8 (round-robin dispatch)
// sees only batches {x, x+8, x+16, x+24} -> h working set 4 x 512 KB = 2 MB,
// resident in that XCD's 4 MB L2. Kills the round-4 8-way L2 replication
// (FETCH_SIZE was 135 MB = 8 x h's 16 MB).
__global__ __launch_bounds__(256, 4) void k_msg(
    const int* __restrict__ idxbuf, const float* __restrict__ es2,
    const float* __restrict__ ed2, const float* __restrict__ h,
    const float* __restrict__ emb, float* __restrict__ obuf,
    float* __restrict__ stats, float* __restrict__ stats2) {
    int g = blockIdx.x;
    int b = (g & 7) + 8 * ((g >> 3) & 3);
    int i0 = (g >> 5) * 32;
    int wid = threadIdx.x >> 6, lane = threadIdx.x & 63;

    const float* hb = h + (size_t)b * N_NODES * D_EMB;
    float acc = 0.f, acc2 = 0.f;

#pragma unroll 1
    for (int it = 0; it < 8; it++) {
        int i = i0 + it * 4 + wid;
        int jk = idxbuf[i * TOPK + (lane < TOPK ? lane : 0)];
        float es_i = es2[i * B_BATCH + b];
        float ev = es_i + ed2[jk * B_BATCH + b];
        ev = ev > 0.f ? ev : NEG_SLOPE * ev;
        float evm = (lane < TOPK) ? ev : -3e38f;
        float m = wave_max(evm);
        float w = (lane < TOPK) ? __expf(ev - m) : 0.f;
        float s = wave_sum(w);
        float alpha = w / s;

        float z = 0.f;
#pragma unroll
        for (int k = 0; k < TOPK; k++) {
            float a = __shfl(alpha, k, 64);
            int j = __shfl(jk, k, 64);
            z = fmaf(a, hb[(size_t)j * D_EMB + lane], z);
        }
        float o = fmaxf(z, 0.f) * emb[i * D_EMB + lane];
        obuf[((size_t)b * N_NODES + i) * D_EMB + lane] = o;
        acc += o;
        acc2 += o * o;
    }

    __shared__ float sa[4][D_EMB], sb[4][D_EMB];
    sa[wid][lane] = acc;
    sb[wid][lane] = acc2;
    __syncthreads();
    if (wid == 0) {
        float su = sa[0][lane] + sa[1][lane] + sa[2][lane] + sa[3][lane];
        float sq = sb[0][lane] + sb[1][lane] + sb[2][lane] + sb[3][lane];
        atomicAdd(&stats[lane * STATS_STRIDE], su);
        atomicAdd(&stats2[lane * STATS_STRIDE], sq);
    }
}

// ---------------- K5: BN apply + relu + fc ---------------------------------
__global__ __launch_bounds__(256) void k_out(
    const float* __restrict__ obuf, const float* __restrict__ stats,
    const float* __restrict__ stats2, const float* __restrict__ gamma,
    const float* __restrict__ beta, const float* __restrict__ fc_w,
    const float* __restrict__ fc_b, float* __restrict__ out) {
    int wid = threadIdx.x >> 6, lane = threadIdx.x & 63;
    int gw = blockIdx.x * 4 + wid;
    const float invM = 1.0f / (float)BN_TOTAL;
    float mean = stats[lane * STATS_STRIDE] * invM;
    float var = stats2[lane * STATS_STRIDE] * invM - mean * mean;
    float inv = rsqrtf(var + EPS_BN);
    float g = gamma[lane], bt = beta[lane], fw = fc_w[lane], fb = fc_b[0];
    for (int node = gw; node < BN_TOTAL; node += 8192) {
        float o = obuf[(size_t)node * D_EMB + lane];
        float v = (o - mean) * inv * g + bt;
        v = fmaxf(v, 0.f);
        float p = wave_sum(v * fw);
        if (lane == 0) out[node] = p + fb;
    }
}

// ---------------- launch ----------------------------------------------------
extern "C" void kernel_launch(void* const* d_in, const int* in_sizes, int n_in,
                              void* d_out, int out_size, void* d_ws, size_t ws_size,
                              hipStream_t stream) {
    const float* x     = (const float*)d_in[0];
    const float* emb   = (const float*)d_in[1];
    const float* W     = (const float*)d_in[2];
    const float* Wb    = (const float*)d_in[3];
    const float* a_src = (const float*)d_in[4];
    const float* a_dst = (const float*)d_in[5];
    const float* gamma = (const float*)d_in[6];
    const float* beta  = (const float*)d_in[7];
    const float* fc_w  = (const float*)d_in[8];
    const float* fc_b  = (const float*)d_in[9];
    float* out = (float*)d_out;

    char* ws = (char*)d_ws;
    float* stats  = (float*)(ws + 0);             // 4 KB
    float* stats2 = (float*)(ws + 4096);          // 4 KB
    int*   idxbuf = (int*)  (ws + 8192);          // 172032 B
    float* norms  = (float*)(ws + 180224);        // 8 KB
    float* es2    = (float*)(ws + 188416);        // 256 KB [N][B]
    float* ed2    = (float*)(ws + 450560);        // 256 KB [N][B]
    float* h      = (float*)(ws + 712704);        // 16 MB [B][N][D]
    float* cosM   = (float*)(ws + 17489920);      // 16 MB — ALIASED with obuf:
    float* obuf   = cosM;                         // cosM dead after k_select
    // total: 34,267,136 bytes

    hipMemsetAsync(stats, 0, 8192, stream);

    k_node_pre<<<N_NODES, 64, 0, stream>>>(emb, norms);
    k_gram<<<1024, 256, 0, stream>>>(emb, norms, cosM);
    k_select<<<N_NODES / 4, 256, 0, stream>>>(cosM, idxbuf);
    k_h<<<2048, 256, 0, stream>>>(x, W, Wb, a_src, a_dst, emb, h, es2, ed2);
    k_msg<<<2048, 256, 0, stream>>>(idxbuf, es2, ed2, h, emb, obuf, stats, stats2);
    k_out<<<2048, 256, 0, stream>>>(obuf, stats, stats2, gamma, beta, fc_w, fc_b, out);
}

// Round 6
// 197.275 us; speedup vs baseline: 1.4916x; 1.0477x over previous
//
#include <hip/hip_runtime.h>
#include <math.h>

#define N_NODES 2048
#define T_WIN 5
#define D_EMB 64
#define TOPK 21
#define B_BATCH 32
#define BN_TOTAL (B_BATCH * N_NODES)   // 65536
#define EPS_BN 1e-5f
#define NEG_SLOPE 0.2f
#define STATS_STRIDE 16

typedef unsigned long long u64;

// ---------------- wave-level helpers (wave = 64 on gfx950) ----------------
__device__ __forceinline__ float wave_sum(float v) {
#pragma unroll
    for (int off = 32; off > 0; off >>= 1) v += __shfl_xor(v, off, 64);
    return v;
}
__device__ __forceinline__ float wave_max(float v) {
#pragma unroll
    for (int off = 32; off > 0; off >>= 1) v = fmaxf(v, __shfl_xor(v, off, 64));
    return v;
}
__device__ __forceinline__ float readlane_f(float v, int l) {
    return __uint_as_float(__builtin_amdgcn_readlane(__float_as_uint(v), l));
}

__device__ __forceinline__ u64 max64(u64 a, u64 b) { return a > b ? a : b; }
__device__ __forceinline__ u64 min64(u64 a, u64 b) { return a < b ? a : b; }

__device__ __forceinline__ u64 bitonic_sort64_desc(u64 key, int lane) {
#pragma unroll
    for (int k = 2; k <= 64; k <<= 1) {
#pragma unroll
        for (int j = k >> 1; j >= 1; j >>= 1) {
            u64 pk = __shfl_xor(key, j, 64);
            bool dirDesc = ((lane & k) == 0);
            bool keepMax = (((lane & j) == 0) == dirDesc);
            key = keepMax ? max64(key, pk) : min64(key, pk);
        }
    }
    return key;
}

__device__ __forceinline__ u64 bitonic_merge_top64(u64 a, u64 b, int lane) {
    u64 br = __shfl(b, 63 - lane, 64);
    u64 c = max64(a, br);
#pragma unroll
    for (int j = 32; j >= 1; j >>= 1) {
        u64 pk = __shfl_xor(c, j, 64);
        bool keepMax = ((lane & j) == 0);
        c = keepMax ? max64(c, pk) : min64(c, pk);
    }
    return c;
}

// ---------------- K1: per-node norms + stats zeroing ------------------------
__global__ __launch_bounds__(64) void k_node_pre(
    const float* __restrict__ emb, float* __restrict__ norms,
    float* __restrict__ stats, float* __restrict__ stats2) {
    int n = blockIdx.x;
    int d = threadIdx.x;
    if (n < 16) stats[n * 64 + d] = 0.f;            // 1024 floats
    else if (n < 32) stats2[(n - 16) * 64 + d] = 0.f;
    float e = emb[n * D_EMB + d];
    float s2 = wave_sum(e * e);
    if (d == 0) norms[n] = sqrtf(s2);
}

// ---------------- K2a: Gram/cos matrix, tiled GEMM --------------------------
__global__ __launch_bounds__(256) void k_gram(
    const float* __restrict__ emb, const float* __restrict__ norms,
    float* __restrict__ cosM) {
    __shared__ __align__(16) float As[64][68];   // [d][i]
    __shared__ __align__(16) float Bs[64][68];   // [d][j]
    int t = threadIdx.x;
    int bi = blockIdx.x & 31, bj = blockIdx.x >> 5;
    int i0 = bi * 64, j0 = bj * 64;

    {   // coalesced stage: lanes 0-3 cover 64 contiguous bytes of one row
        int r = t >> 2, c0 = t & 3;
        const float4* srcA = (const float4*)(emb + (size_t)(i0 + r) * D_EMB);
        const float4* srcB = (const float4*)(emb + (size_t)(j0 + r) * D_EMB);
#pragma unroll
        for (int k = 0; k < 4; k++) {
            int f4 = c0 + 4 * k;
            float4 v = srcA[f4];
            int d = 4 * f4;
            As[d][r] = v.x; As[d + 1][r] = v.y; As[d + 2][r] = v.z; As[d + 3][r] = v.w;
            float4 w = srcB[f4];
            Bs[d][r] = w.x; Bs[d + 1][r] = w.y; Bs[d + 2][r] = w.z; Bs[d + 3][r] = w.w;
        }
    }
    __syncthreads();

    int ti = t & 15, tj = t >> 4;
    float acc[4][4] = {};
#pragma unroll
    for (int d = 0; d < 64; d++) {
        float4 a = *(const float4*)&As[d][4 * ti];
        float4 b = *(const float4*)&Bs[d][4 * tj];
        acc[0][0] += a.x * b.x; acc[0][1] += a.x * b.y; acc[0][2] += a.x * b.z; acc[0][3] += a.x * b.w;
        acc[1][0] += a.y * b.x; acc[1][1] += a.y * b.y; acc[1][2] += a.y * b.z; acc[1][3] += a.y * b.w;
        acc[2][0] += a.z * b.x; acc[2][1] += a.z * b.y; acc[2][2] += a.z * b.z; acc[2][3] += a.z * b.w;
        acc[3][0] += a.w * b.x; acc[3][1] += a.w * b.y; acc[3][2] += a.w * b.z; acc[3][3] += a.w * b.w;
    }

    float nis[4] = {norms[i0 + 4 * ti], norms[i0 + 4 * ti + 1],
                    norms[i0 + 4 * ti + 2], norms[i0 + 4 * ti + 3]};
    float njs[4] = {norms[j0 + 4 * tj], norms[j0 + 4 * tj + 1],
                    norms[j0 + 4 * tj + 2], norms[j0 + 4 * tj + 3]};
#pragma unroll
    for (int r = 0; r < 4; r++) {
        float4 o;
        o.x = acc[r][0] / (nis[r] * njs[0]);
        o.y = acc[r][1] / (nis[r] * njs[1]);
        o.z = acc[r][2] / (nis[r] * njs[2]);
        o.w = acc[r][3] / (nis[r] * njs[3]);
        *(float4*)(cosM + (size_t)(i0 + 4 * ti + r) * N_NODES + j0 + 4 * tj) = o;
    }
}

// ---------------- K2b: top-21 selection (streaming filter, prefetched) ------
__global__ __launch_bounds__(256) void k_select(
    const float* __restrict__ cosM, int* __restrict__ idxbuf) {
    __shared__ u64 candbuf[4][128];
    int tid = threadIdx.x;
    int wid = tid >> 6, lane = tid & 63;
    int i = blockIdx.x * 4 + wid;
    const float* row = cosM + (size_t)i * N_NODES;
    u64* buf = candbuf[wid];

    u64 a = 0;
    u64 t = 0;
    int cnt = 0;
    float vcur = row[lane];   // prefetch chunk 0

#pragma unroll 1
    for (int c = 0; c < N_NODES / 64; c++) {
        int j = c * 64 + lane;
        float v = vcur;
        if (c < N_NODES / 64 - 1) vcur = row[j + 64];   // hoisted above branch
        unsigned u = __float_as_uint(v);
        u = (u & 0x80000000u) ? ~u : (u | 0x80000000u);
        u64 key = ((u64)u << 32) | (unsigned)(~j);
        unsigned long long ball = __ballot(key > t);
        if (ball) {
            int ofs = __popcll(ball & ((1ull << lane) - 1ull));
            if (key > t) buf[cnt + ofs] = key;
            cnt += (int)__popcll(ball);
            if (cnt >= 64) {
                u64 nk = buf[lane];
                nk = bitonic_sort64_desc(nk, lane);
                a = bitonic_merge_top64(a, nk, lane);
                t = __shfl(a, 20, 64);
                int rem = cnt - 64;
                u64 mv = (lane < rem) ? buf[64 + lane] : 0;
                if (lane < rem) buf[lane] = mv;
                cnt = rem;
            }
        }
    }
    while (cnt > 0) {
        int take = cnt < 64 ? cnt : 64;
        u64 nk = (lane < take) ? buf[lane] : 0;
        nk = bitonic_sort64_desc(nk, lane);
        a = bitonic_merge_top64(a, nk, lane);
        t = __shfl(a, 20, 64);
        int rem = cnt - take;
        u64 mv = (lane < rem) ? buf[take + lane] : 0;
        if (lane < rem) buf[lane] = mv;
        cnt = rem;
    }

    if (lane < TOPK) idxbuf[i * TOPK + lane] = (int)(~(unsigned)a);
}

// ---------------- K3: h[B][N][D] = x@W^T + Wb ; es2/ed2 [N][B] --------------
__global__ __launch_bounds__(256) void k_h(
    const float* __restrict__ x, const float* __restrict__ W,
    const float* __restrict__ Wb, const float* __restrict__ a_src,
    const float* __restrict__ a_dst, const float* __restrict__ emb,
    float* __restrict__ h, float* __restrict__ es2, float* __restrict__ ed2) {
    int wid = threadIdx.x >> 6, lane = threadIdx.x & 63;
    int gw = blockIdx.x * 4 + wid;
    const float* wp = W + lane * T_WIN;
    float w0 = wp[0], w1 = wp[1], w2 = wp[2], w3 = wp[3], w4 = wp[4];
    float bias = Wb[lane];
    float as = a_src[lane], asE = a_src[D_EMB + lane];
    float ad = a_dst[lane], adE = a_dst[D_EMB + lane];

    for (int node = gw; node < BN_TOTAL; node += 8192) {
        int b = node >> 11;
        int n = node & (N_NODES - 1);
        const float* xp = x + (size_t)node * T_WIN;
        float hv = bias + xp[0] * w0 + xp[1] * w1 + xp[2] * w2 + xp[3] * w3 + xp[4] * w4;
        float e = emb[n * D_EMB + lane];
        h[(size_t)node * D_EMB + lane] = hv;     // [B][N][D]
        float es = wave_sum(hv * as + e * asE);
        float ed = wave_sum(hv * ad + e * adE);
        if (lane == 0) {
            es2[n * B_BATCH + b] = es;
            ed2[n * B_BATCH + b] = ed;
        }
    }
}

// ---------------- K4: message passing, XCD-local, readlane gather -----------
// b = (g&7)+8*((g>>3)&3): each XCD sees 4 batches -> h working set 2 MB,
// L2-resident (round 5: FETCH 135->13 MB, proven). Round 6: the gather loop's
// 2 ds_bpermute/k are replaced by v_readlane to SGPRs (literal lane index,
// VALU pipe) -> saddr-form global loads, 21 independent loads per item, 2
// items in flight, 2 fma chains per item.
__global__ __launch_bounds__(256, 6) void k_msg(
    const int* __restrict__ idxbuf, const float* __restrict__ es2,
    const float* __restrict__ ed2, const float* __restrict__ h,
    const float* __restrict__ emb, float* __restrict__ obuf,
    float* __restrict__ stats, float* __restrict__ stats2) {
    int g = blockIdx.x;
    int b = (g & 7) + 8 * ((g >> 3) & 3);
    int i0 = (g >> 5) * 32;
    int wid = threadIdx.x >> 6, lane = threadIdx.x & 63;

    const float* hb = h + (size_t)b * N_NODES * D_EMB;
    float acc = 0.f, acc2 = 0.f;

#pragma unroll 1
    for (int it = 0; it < 8; it += 2) {
        int iA = i0 + it * 4 + wid;
        int iB = iA + 4;

        int lk = (lane < TOPK) ? lane : 0;
        int jkA = idxbuf[iA * TOPK + lk];
        int jkB = idxbuf[iB * TOPK + lk];
        float evA = es2[iA * B_BATCH + b] + ed2[jkA * B_BATCH + b];
        float evB = es2[iB * B_BATCH + b] + ed2[jkB * B_BATCH + b];
        evA = evA > 0.f ? evA : NEG_SLOPE * evA;
        evB = evB > 0.f ? evB : NEG_SLOPE * evB;
        float mA = wave_max((lane < TOPK) ? evA : -3e38f);
        float mB = wave_max((lane < TOPK) ? evB : -3e38f);
        float wA = (lane < TOPK) ? __expf(evA - mA) : 0.f;
        float wB = (lane < TOPK) ? __expf(evB - mB) : 0.f;
        float alphaA = wA / wave_sum(wA);
        float alphaB = wB / wave_sum(wB);

        float zA0 = 0.f, zA1 = 0.f, zB0 = 0.f, zB1 = 0.f;
#pragma unroll
        for (int k = 0; k < TOPK; k += 2) {
            {
                int j = __builtin_amdgcn_readlane(jkA, k);
                float a = readlane_f(alphaA, k);
                zA0 = fmaf(a, hb[(size_t)j * D_EMB + lane], zA0);
            }
            if (k + 1 < TOPK) {
                int j = __builtin_amdgcn_readlane(jkA, k + 1);
                float a = readlane_f(alphaA, k + 1);
                zA1 = fmaf(a, hb[(size_t)j * D_EMB + lane], zA1);
            }
            {
                int j = __builtin_amdgcn_readlane(jkB, k);
                float a = readlane_f(alphaB, k);
                zB0 = fmaf(a, hb[(size_t)j * D_EMB + lane], zB0);
            }
            if (k + 1 < TOPK) {
                int j = __builtin_amdgcn_readlane(jkB, k + 1);
                float a = readlane_f(alphaB, k + 1);
                zB1 = fmaf(a, hb[(size_t)j * D_EMB + lane], zB1);
            }
        }
        float oA = fmaxf(zA0 + zA1, 0.f) * emb[iA * D_EMB + lane];
        float oB = fmaxf(zB0 + zB1, 0.f) * emb[iB * D_EMB + lane];
        obuf[((size_t)b * N_NODES + iA) * D_EMB + lane] = oA;
        obuf[((size_t)b * N_NODES + iB) * D_EMB + lane] = oB;
        acc += oA + oB;
        acc2 += oA * oA + oB * oB;
    }

    __shared__ float sa[4][D_EMB], sb[4][D_EMB];
    sa[wid][lane] = acc;
    sb[wid][lane] = acc2;
    __syncthreads();
    if (wid == 0) {
        float su = sa[0][lane] + sa[1][lane] + sa[2][lane] + sa[3][lane];
        float sq = sb[0][lane] + sb[1][lane] + sb[2][lane] + sb[3][lane];
        atomicAdd(&stats[lane * STATS_STRIDE], su);
        atomicAdd(&stats2[lane * STATS_STRIDE], sq);
    }
}

// ---------------- K5: BN apply + relu + fc ---------------------------------
__global__ __launch_bounds__(256) void k_out(
    const float* __restrict__ obuf, const float* __restrict__ stats,
    const float* __restrict__ stats2, const float* __restrict__ gamma,
    const float* __restrict__ beta, const float* __restrict__ fc_w,
    const float* __restrict__ fc_b, float* __restrict__ out) {
    int wid = threadIdx.x >> 6, lane = threadIdx.x & 63;
    int gw = blockIdx.x * 4 + wid;
    const float invM = 1.0f / (float)BN_TOTAL;
    float mean = stats[lane * STATS_STRIDE] * invM;
    float var = stats2[lane * STATS_STRIDE] * invM - mean * mean;
    float inv = rsqrtf(var + EPS_BN);
    float g = gamma[lane], bt = beta[lane], fw = fc_w[lane], fb = fc_b[0];
    for (int node = gw; node < BN_TOTAL; node += 8192) {
        float o = obuf[(size_t)node * D_EMB + lane];
        float v = (o - mean) * inv * g + bt;
        v = fmaxf(v, 0.f);
        float p = wave_sum(v * fw);
        if (lane == 0) out[node] = p + fb;
    }
}

// ---------------- launch ----------------------------------------------------
extern "C" void kernel_launch(void* const* d_in, const int* in_sizes, int n_in,
                              void* d_out, int out_size, void* d_ws, size_t ws_size,
                              hipStream_t stream) {
    const float* x     = (const float*)d_in[0];
    const float* emb   = (const float*)d_in[1];
    const float* W     = (const float*)d_in[2];
    const float* Wb    = (const float*)d_in[3];
    const float* a_src = (const float*)d_in[4];
    const float* a_dst = (const float*)d_in[5];
    const float* gamma = (const float*)d_in[6];
    const float* beta  = (const float*)d_in[7];
    const float* fc_w  = (const float*)d_in[8];
    const float* fc_b  = (const float*)d_in[9];
    float* out = (float*)d_out;

    char* ws = (char*)d_ws;
    float* stats  = (float*)(ws + 0);             // 4 KB
    float* stats2 = (float*)(ws + 4096);          // 4 KB
    int*   idxbuf = (int*)  (ws + 8192);          // 172032 B
    float* norms  = (float*)(ws + 180224);        // 8 KB
    float* es2    = (float*)(ws + 188416);        // 256 KB [N][B]
    float* ed2    = (float*)(ws + 450560);        // 256 KB [N][B]
    float* h      = (float*)(ws + 712704);        // 16 MB [B][N][D]
    float* cosM   = (float*)(ws + 17489920);      // 16 MB — ALIASED with obuf
    float* obuf   = cosM;                         // (cosM dead after k_select)
    // total: 34,267,136 bytes

    k_node_pre<<<N_NODES, 64, 0, stream>>>(emb, norms, stats, stats2);
    k_gram<<<1024, 256, 0, stream>>>(emb, norms, cosM);
    k_select<<<N_NODES / 4, 256, 0, stream>>>(cosM, idxbuf);
    k_h<<<2048, 256, 0, stream>>>(x, W, Wb, a_src, a_dst, emb, h, es2, ed2);
    k_msg<<<2048, 256, 0, stream>>>(idxbuf, es2, ed2, h, emb, obuf, stats, stats2);
    k_out<<<2048, 256, 0, stream>>>(obuf, stats, stats2, gamma, beta, fc_w, fc_b, out);
}

// Round 7
// 195.700 us; speedup vs baseline: 1.5036x; 1.0081x over previous
//
#include <hip/hip_runtime.h>
#include <math.h>

#define N_NODES 2048
#define T_WIN 5
#define D_EMB 64
#define TOPK 21
#define B_BATCH 32
#define BN_TOTAL (B_BATCH * N_NODES)   // 65536
#define EPS_BN 1e-5f
#define NEG_SLOPE 0.2f
#define STATS_STRIDE 16

typedef unsigned long long u64;

// ---------------- wave-level helpers (wave = 64 on gfx950) ----------------
__device__ __forceinline__ float wave_sum(float v) {
#pragma unroll
    for (int off = 32; off > 0; off >>= 1) v += __shfl_xor(v, off, 64);
    return v;
}
__device__ __forceinline__ float wave_max(float v) {
#pragma unroll
    for (int off = 32; off > 0; off >>= 1) v = fmaxf(v, __shfl_xor(v, off, 64));
    return v;
}
__device__ __forceinline__ float readlane_f(float v, int l) {
    return __uint_as_float(__builtin_amdgcn_readlane(__float_as_uint(v), l));
}

__device__ __forceinline__ u64 max64(u64 a, u64 b) { return a > b ? a : b; }
__device__ __forceinline__ u64 min64(u64 a, u64 b) { return a < b ? a : b; }

__device__ __forceinline__ u64 bitonic_sort64_desc(u64 key, int lane) {
#pragma unroll
    for (int k = 2; k <= 64; k <<= 1) {
#pragma unroll
        for (int j = k >> 1; j >= 1; j >>= 1) {
            u64 pk = __shfl_xor(key, j, 64);
            bool dirDesc = ((lane & k) == 0);
            bool keepMax = (((lane & j) == 0) == dirDesc);
            key = keepMax ? max64(key, pk) : min64(key, pk);
        }
    }
    return key;
}

__device__ __forceinline__ u64 bitonic_merge_top64(u64 a, u64 b, int lane) {
    u64 br = __shfl(b, 63 - lane, 64);
    u64 c = max64(a, br);
#pragma unroll
    for (int j = 32; j >= 1; j >>= 1) {
        u64 pk = __shfl_xor(c, j, 64);
        bool keepMax = ((lane & j) == 0);
        c = keepMax ? max64(c, pk) : min64(c, pk);
    }
    return c;
}

// ---------------- K1: per-node norms + stats zeroing ------------------------
__global__ __launch_bounds__(64) void k_node_pre(
    const float* __restrict__ emb, float* __restrict__ norms,
    float* __restrict__ stats, float* __restrict__ stats2) {
    int n = blockIdx.x;
    int d = threadIdx.x;
    if (n < 16) stats[n * 64 + d] = 0.f;
    else if (n < 32) stats2[(n - 16) * 64 + d] = 0.f;
    float e = emb[n * D_EMB + d];
    float s2 = wave_sum(e * e);
    if (d == 0) norms[n] = sqrtf(s2);
}

// ---------------- K2a: Gram/cos matrix, tiled GEMM --------------------------
__global__ __launch_bounds__(256) void k_gram(
    const float* __restrict__ emb, const float* __restrict__ norms,
    float* __restrict__ cosM) {
    __shared__ __align__(16) float As[64][68];   // [d][i]
    __shared__ __align__(16) float Bs[64][68];   // [d][j]
    int t = threadIdx.x;
    int bi = blockIdx.x & 31, bj = blockIdx.x >> 5;
    int i0 = bi * 64, j0 = bj * 64;

    {
        int r = t >> 2, c0 = t & 3;
        const float4* srcA = (const float4*)(emb + (size_t)(i0 + r) * D_EMB);
        const float4* srcB = (const float4*)(emb + (size_t)(j0 + r) * D_EMB);
#pragma unroll
        for (int k = 0; k < 4; k++) {
            int f4 = c0 + 4 * k;
            float4 v = srcA[f4];
            int d = 4 * f4;
            As[d][r] = v.x; As[d + 1][r] = v.y; As[d + 2][r] = v.z; As[d + 3][r] = v.w;
            float4 w = srcB[f4];
            Bs[d][r] = w.x; Bs[d + 1][r] = w.y; Bs[d + 2][r] = w.z; Bs[d + 3][r] = w.w;
        }
    }
    __syncthreads();

    int ti = t & 15, tj = t >> 4;
    float acc[4][4] = {};
#pragma unroll
    for (int d = 0; d < 64; d++) {
        float4 a = *(const float4*)&As[d][4 * ti];
        float4 b = *(const float4*)&Bs[d][4 * tj];
        acc[0][0] += a.x * b.x; acc[0][1] += a.x * b.y; acc[0][2] += a.x * b.z; acc[0][3] += a.x * b.w;
        acc[1][0] += a.y * b.x; acc[1][1] += a.y * b.y; acc[1][2] += a.y * b.z; acc[1][3] += a.y * b.w;
        acc[2][0] += a.z * b.x; acc[2][1] += a.z * b.y; acc[2][2] += a.z * b.z; acc[2][3] += a.z * b.w;
        acc[3][0] += a.w * b.x; acc[3][1] += a.w * b.y; acc[3][2] += a.w * b.z; acc[3][3] += a.w * b.w;
    }

    float nis[4] = {norms[i0 + 4 * ti], norms[i0 + 4 * ti + 1],
                    norms[i0 + 4 * ti + 2], norms[i0 + 4 * ti + 3]};
    float njs[4] = {norms[j0 + 4 * tj], norms[j0 + 4 * tj + 1],
                    norms[j0 + 4 * tj + 2], norms[j0 + 4 * tj + 3]};
#pragma unroll
    for (int r = 0; r < 4; r++) {
        float4 o;
        o.x = acc[r][0] / (nis[r] * njs[0]);
        o.y = acc[r][1] / (nis[r] * njs[1]);
        o.z = acc[r][2] / (nis[r] * njs[2]);
        o.w = acc[r][3] / (nis[r] * njs[3]);
        *(float4*)(cosM + (size_t)(i0 + 4 * ti + r) * N_NODES + j0 + 4 * tj) = o;
    }
}

// ---------------- K2b: top-21 selection (streaming filter, prefetched) ------
__global__ __launch_bounds__(256) void k_select(
    const float* __restrict__ cosM, int* __restrict__ idxbuf) {
    __shared__ u64 candbuf[4][128];
    int tid = threadIdx.x;
    int wid = tid >> 6, lane = tid & 63;
    int i = blockIdx.x * 4 + wid;
    const float* row = cosM + (size_t)i * N_NODES;
    u64* buf = candbuf[wid];

    u64 a = 0;
    u64 t = 0;
    int cnt = 0;
    float vcur = row[lane];

#pragma unroll 1
    for (int c = 0; c < N_NODES / 64; c++) {
        int j = c * 64 + lane;
        float v = vcur;
        if (c < N_NODES / 64 - 1) vcur = row[j + 64];
        unsigned u = __float_as_uint(v);
        u = (u & 0x80000000u) ? ~u : (u | 0x80000000u);
        u64 key = ((u64)u << 32) | (unsigned)(~j);
        unsigned long long ball = __ballot(key > t);
        if (ball) {
            int ofs = __popcll(ball & ((1ull << lane) - 1ull));
            if (key > t) buf[cnt + ofs] = key;
            cnt += (int)__popcll(ball);
            if (cnt >= 64) {
                u64 nk = buf[lane];
                nk = bitonic_sort64_desc(nk, lane);
                a = bitonic_merge_top64(a, nk, lane);
                t = __shfl(a, 20, 64);
                int rem = cnt - 64;
                u64 mv = (lane < rem) ? buf[64 + lane] : 0;
                if (lane < rem) buf[lane] = mv;
                cnt = rem;
            }
        }
    }
    while (cnt > 0) {
        int take = cnt < 64 ? cnt : 64;
        u64 nk = (lane < take) ? buf[lane] : 0;
        nk = bitonic_sort64_desc(nk, lane);
        a = bitonic_merge_top64(a, nk, lane);
        t = __shfl(a, 20, 64);
        int rem = cnt - take;
        u64 mv = (lane < rem) ? buf[take + lane] : 0;
        if (lane < rem) buf[lane] = mv;
        cnt = rem;
    }

    if (lane < TOPK) idxbuf[i * TOPK + lane] = (int)(~(unsigned)a);
}

// ---------------- K3: h[B][N][D] = x@W^T + Wb ; es2/ed2 [N][B] --------------
__global__ __launch_bounds__(256) void k_h(
    const float* __restrict__ x, const float* __restrict__ W,
    const float* __restrict__ Wb, const float* __restrict__ a_src,
    const float* __restrict__ a_dst, const float* __restrict__ emb,
    float* __restrict__ h, float* __restrict__ es2, float* __restrict__ ed2) {
    int wid = threadIdx.x >> 6, lane = threadIdx.x & 63;
    int gw = blockIdx.x * 4 + wid;
    const float* wp = W + lane * T_WIN;
    float w0 = wp[0], w1 = wp[1], w2 = wp[2], w3 = wp[3], w4 = wp[4];
    float bias = Wb[lane];
    float as = a_src[lane], asE = a_src[D_EMB + lane];
    float ad = a_dst[lane], adE = a_dst[D_EMB + lane];

    for (int node = gw; node < BN_TOTAL; node += 8192) {
        int b = node >> 11;
        int n = node & (N_NODES - 1);
        const float* xp = x + (size_t)node * T_WIN;
        float hv = bias + xp[0] * w0 + xp[1] * w1 + xp[2] * w2 + xp[3] * w3 + xp[4] * w4;
        float e = emb[n * D_EMB + lane];
        h[(size_t)node * D_EMB + lane] = hv;     // [B][N][D]
        float es = wave_sum(hv * as + e * asE);
        float ed = wave_sum(hv * ad + e * adE);
        if (lane == 0) {
            es2[n * B_BATCH + b] = es;
            ed2[n * B_BATCH + b] = ed;
        }
    }
}

// ---------------- K4: message passing — phase-split, full unroll ------------
// Round-7 experiment: SAME traffic, SAME grid/mapping/stats as round 6; the
// ONLY change is structure. Phase 1 computes all 8 items' (jk, alpha) into
// register arrays — 8 independent softmax chains the compiler can interleave
// (round 6's unroll-1 loop forced one ~2K-cycle serial chain per item).
// Phase 2 is a fully-unrolled 168-load gather: 16 independent fma chains,
// no shuffle/LDS op anywhere between loads.
__global__ __launch_bounds__(256, 4) void k_msg(
    const int* __restrict__ idxbuf, const float* __restrict__ es2,
    const float* __restrict__ ed2, const float* __restrict__ h,
    const float* __restrict__ emb, float* __restrict__ obuf,
    float* __restrict__ stats, float* __restrict__ stats2) {
    int g = blockIdx.x;
    int b = (g & 7) + 8 * ((g >> 3) & 3);   // XCD-local batches (r5: FETCH 135->13 MB)
    int i0 = (g >> 5) * 32;
    int wid = threadIdx.x >> 6, lane = threadIdx.x & 63;
    const float* hb = h + (size_t)b * N_NODES * D_EMB;

    int jk[8];
    float al[8];
    int lk = (lane < TOPK) ? lane : 0;

    // ---- phase 1: 8 independent softmax chains ----
#pragma unroll
    for (int it = 0; it < 8; it++) {
        int i = i0 + it * 4 + wid;
        jk[it] = idxbuf[i * TOPK + lk];
        float ev = es2[i * B_BATCH + b] + ed2[jk[it] * B_BATCH + b];
        ev = ev > 0.f ? ev : NEG_SLOPE * ev;
        float m = wave_max((lane < TOPK) ? ev : -3e38f);
        float w = (lane < TOPK) ? __expf(ev - m) : 0.f;
        al[it] = w / wave_sum(w);
    }

    // ---- phase 2: fully-unrolled gather, 2 fma chains per item ----
    float acc = 0.f, acc2 = 0.f;
#pragma unroll
    for (int it = 0; it < 8; it++) {
        float z0 = 0.f, z1 = 0.f;
#pragma unroll
        for (int k = 0; k < TOPK; k += 2) {
            int j0 = __builtin_amdgcn_readlane(jk[it], k);
            float a0 = readlane_f(al[it], k);
            z0 = fmaf(a0, hb[(size_t)j0 * D_EMB + lane], z0);
            if (k + 1 < TOPK) {
                int j1 = __builtin_amdgcn_readlane(jk[it], k + 1);
                float a1 = readlane_f(al[it], k + 1);
                z1 = fmaf(a1, hb[(size_t)j1 * D_EMB + lane], z1);
            }
        }
        int i = i0 + it * 4 + wid;
        float o = fmaxf(z0 + z1, 0.f) * emb[i * D_EMB + lane];
        obuf[((size_t)b * N_NODES + i) * D_EMB + lane] = o;
        acc += o;
        acc2 += o * o;
    }

    __shared__ float sa[4][D_EMB], sb[4][D_EMB];
    sa[wid][lane] = acc;
    sb[wid][lane] = acc2;
    __syncthreads();
    if (wid == 0) {
        float su = sa[0][lane] + sa[1][lane] + sa[2][lane] + sa[3][lane];
        float sq = sb[0][lane] + sb[1][lane] + sb[2][lane] + sb[3][lane];
        atomicAdd(&stats[lane * STATS_STRIDE], su);
        atomicAdd(&stats2[lane * STATS_STRIDE], sq);
    }
}

// ---------------- K5: BN apply + relu + fc ---------------------------------
__global__ __launch_bounds__(256) void k_out(
    const float* __restrict__ obuf, const float* __restrict__ stats,
    const float* __restrict__ stats2, const float* __restrict__ gamma,
    const float* __restrict__ beta, const float* __restrict__ fc_w,
    const float* __restrict__ fc_b, float* __restrict__ out) {
    int wid = threadIdx.x >> 6, lane = threadIdx.x & 63;
    int gw = blockIdx.x * 4 + wid;
    const float invM = 1.0f / (float)BN_TOTAL;
    float mean = stats[lane * STATS_STRIDE] * invM;
    float var = stats2[lane * STATS_STRIDE] * invM - mean * mean;
    float inv = rsqrtf(var + EPS_BN);
    float g = gamma[lane], bt = beta[lane], fw = fc_w[lane], fb = fc_b[0];
    for (int node = gw; node < BN_TOTAL; node += 8192) {
        float o = obuf[(size_t)node * D_EMB + lane];
        float v = (o - mean) * inv * g + bt;
        v = fmaxf(v, 0.f);
        float p = wave_sum(v * fw);
        if (lane == 0) out[node] = p + fb;
    }
}

// ---------------- launch ----------------------------------------------------
extern "C" void kernel_launch(void* const* d_in, const int* in_sizes, int n_in,
                              void* d_out, int out_size, void* d_ws, size_t ws_size,
                              hipStream_t stream) {
    const float* x     = (const float*)d_in[0];
    const float* emb   = (const float*)d_in[1];
    const float* W     = (const float*)d_in[2];
    const float* Wb    = (const float*)d_in[3];
    const float* a_src = (const float*)d_in[4];
    const float* a_dst = (const float*)d_in[5];
    const float* gamma = (const float*)d_in[6];
    const float* beta  = (const float*)d_in[7];
    const float* fc_w  = (const float*)d_in[8];
    const float* fc_b  = (const float*)d_in[9];
    float* out = (float*)d_out;

    char* ws = (char*)d_ws;
    float* stats  = (float*)(ws + 0);             // 4 KB
    float* stats2 = (float*)(ws + 4096);          // 4 KB
    int*   idxbuf = (int*)  (ws + 8192);          // 172032 B
    float* norms  = (float*)(ws + 180224);        // 8 KB
    float* es2    = (float*)(ws + 188416);        // 256 KB [N][B]
    float* ed2    = (float*)(ws + 450560);        // 256 KB [N][B]
    float* h      = (float*)(ws + 712704);        // 16 MB [B][N][D]
    float* cosM   = (float*)(ws + 17489920);      // 16 MB — ALIASED with obuf
    float* obuf   = cosM;                         // (cosM dead after k_select)
    // total: 34,267,136 bytes

    k_node_pre<<<N_NODES, 64, 0, stream>>>(emb, norms, stats, stats2);
    k_gram<<<1024, 256, 0, stream>>>(emb, norms, cosM);
    k_select<<<N_NODES / 4, 256, 0, stream>>>(cosM, idxbuf);
    k_h<<<2048, 256, 0, stream>>>(x, W, Wb, a_src, a_dst, emb, h, es2, ed2);
    k_msg<<<2048, 256, 0, stream>>>(idxbuf, es2, ed2, h, emb, obuf, stats, stats2);
    k_out<<<2048, 256, 0, stream>>>(obuf, stats, stats2, gamma, beta, fc_w, fc_b, out);
}

// Round 8
// 156.070 us; speedup vs baseline: 1.8854x; 1.2539x over previous
//
#include <hip/hip_runtime.h>
#include <math.h>

#define N_NODES 2048
#define T_WIN 5
#define D_EMB 64
#define TOPK 21
#define B_BATCH 32
#define BN_TOTAL (B_BATCH * N_NODES)   // 65536
#define EPS_BN 1e-5f
#define NEG_SLOPE 0.2f
#define STATS_STRIDE 16

typedef unsigned long long u64;

// ---------------- wave-level helpers (wave = 64 on gfx950) ----------------
__device__ __forceinline__ float wave_sum(float v) {
#pragma unroll
    for (int off = 32; off > 0; off >>= 1) v += __shfl_xor(v, off, 64);
    return v;
}

__device__ __forceinline__ u64 max64(u64 a, u64 b) { return a > b ? a : b; }
__device__ __forceinline__ u64 min64(u64 a, u64 b) { return a < b ? a : b; }

__device__ __forceinline__ u64 bitonic_sort64_desc(u64 key, int lane) {
#pragma unroll
    for (int k = 2; k <= 64; k <<= 1) {
#pragma unroll
        for (int j = k >> 1; j >= 1; j >>= 1) {
            u64 pk = __shfl_xor(key, j, 64);
            bool dirDesc = ((lane & k) == 0);
            bool keepMax = (((lane & j) == 0) == dirDesc);
            key = keepMax ? max64(key, pk) : min64(key, pk);
        }
    }
    return key;
}

__device__ __forceinline__ u64 bitonic_merge_top64(u64 a, u64 b, int lane) {
    u64 br = __shfl(b, 63 - lane, 64);
    u64 c = max64(a, br);
#pragma unroll
    for (int j = 32; j >= 1; j >>= 1) {
        u64 pk = __shfl_xor(c, j, 64);
        bool keepMax = ((lane & j) == 0);
        c = keepMax ? max64(c, pk) : min64(c, pk);
    }
    return c;
}

// ---------------- K1: per-node norms + stats zeroing ------------------------
__global__ __launch_bounds__(64) void k_node_pre(
    const float* __restrict__ emb, float* __restrict__ norms,
    float* __restrict__ stats, float* __restrict__ stats2) {
    int n = blockIdx.x;
    int d = threadIdx.x;
    if (n < 16) stats[n * 64 + d] = 0.f;
    else if (n < 32) stats2[(n - 16) * 64 + d] = 0.f;
    float e = emb[n * D_EMB + d];
    float s2 = wave_sum(e * e);
    if (d == 0) norms[n] = sqrtf(s2);
}

// ---------------- K2a: Gram/cos matrix, tiled GEMM --------------------------
// UNCHANGED numerics since r4 — cos bits feed the discrete top-k path.
__global__ __launch_bounds__(256) void k_gram(
    const float* __restrict__ emb, const float* __restrict__ norms,
    float* __restrict__ cosM) {
    __shared__ __align__(16) float As[64][68];   // [d][i]
    __shared__ __align__(16) float Bs[64][68];   // [d][j]
    int t = threadIdx.x;
    int bi = blockIdx.x & 31, bj = blockIdx.x >> 5;
    int i0 = bi * 64, j0 = bj * 64;

    {
        int r = t >> 2, c0 = t & 3;
        const float4* srcA = (const float4*)(emb + (size_t)(i0 + r) * D_EMB);
        const float4* srcB = (const float4*)(emb + (size_t)(j0 + r) * D_EMB);
#pragma unroll
        for (int k = 0; k < 4; k++) {
            int f4 = c0 + 4 * k;
            float4 v = srcA[f4];
            int d = 4 * f4;
            As[d][r] = v.x; As[d + 1][r] = v.y; As[d + 2][r] = v.z; As[d + 3][r] = v.w;
            float4 w = srcB[f4];
            Bs[d][r] = w.x; Bs[d + 1][r] = w.y; Bs[d + 2][r] = w.z; Bs[d + 3][r] = w.w;
        }
    }
    __syncthreads();

    int ti = t & 15, tj = t >> 4;
    float acc[4][4] = {};
#pragma unroll
    for (int d = 0; d < 64; d++) {
        float4 a = *(const float4*)&As[d][4 * ti];
        float4 b = *(const float4*)&Bs[d][4 * tj];
        acc[0][0] += a.x * b.x; acc[0][1] += a.x * b.y; acc[0][2] += a.x * b.z; acc[0][3] += a.x * b.w;
        acc[1][0] += a.y * b.x; acc[1][1] += a.y * b.y; acc[1][2] += a.y * b.z; acc[1][3] += a.y * b.w;
        acc[2][0] += a.z * b.x; acc[2][1] += a.z * b.y; acc[2][2] += a.z * b.z; acc[2][3] += a.z * b.w;
        acc[3][0] += a.w * b.x; acc[3][1] += a.w * b.y; acc[3][2] += a.w * b.z; acc[3][3] += a.w * b.w;
    }

    float nis[4] = {norms[i0 + 4 * ti], norms[i0 + 4 * ti + 1],
                    norms[i0 + 4 * ti + 2], norms[i0 + 4 * ti + 3]};
    float njs[4] = {norms[j0 + 4 * tj], norms[j0 + 4 * tj + 1],
                    norms[j0 + 4 * tj + 2], norms[j0 + 4 * tj + 3]};
#pragma unroll
    for (int r = 0; r < 4; r++) {
        float4 o;
        o.x = acc[r][0] / (nis[r] * njs[0]);
        o.y = acc[r][1] / (nis[r] * njs[1]);
        o.z = acc[r][2] / (nis[r] * njs[2]);
        o.w = acc[r][3] / (nis[r] * njs[3]);
        *(float4*)(cosM + (size_t)(i0 + 4 * ti + r) * N_NODES + j0 + 4 * tj) = o;
    }
}

// ---------------- K2b: top-21 selection -> idxT[k][i] (transposed) ----------
__global__ __launch_bounds__(256) void k_select(
    const float* __restrict__ cosM, int* __restrict__ idxT) {
    __shared__ u64 candbuf[4][128];
    int tid = threadIdx.x;
    int wid = tid >> 6, lane = tid & 63;
    int i = blockIdx.x * 4 + wid;
    const float* row = cosM + (size_t)i * N_NODES;
    u64* buf = candbuf[wid];

    u64 a = 0;
    u64 t = 0;
    int cnt = 0;
    float vcur = row[lane];

#pragma unroll 1
    for (int c = 0; c < N_NODES / 64; c++) {
        int j = c * 64 + lane;
        float v = vcur;
        if (c < N_NODES / 64 - 1) vcur = row[j + 64];
        unsigned u = __float_as_uint(v);
        u = (u & 0x80000000u) ? ~u : (u | 0x80000000u);
        u64 key = ((u64)u << 32) | (unsigned)(~j);
        unsigned long long ball = __ballot(key > t);
        if (ball) {
            int ofs = __popcll(ball & ((1ull << lane) - 1ull));
            if (key > t) buf[cnt + ofs] = key;
            cnt += (int)__popcll(ball);
            if (cnt >= 64) {
                u64 nk = buf[lane];
                nk = bitonic_sort64_desc(nk, lane);
                a = bitonic_merge_top64(a, nk, lane);
                t = __shfl(a, 20, 64);
                int rem = cnt - 64;
                u64 mv = (lane < rem) ? buf[64 + lane] : 0;
                if (lane < rem) buf[lane] = mv;
                cnt = rem;
            }
        }
    }
    while (cnt > 0) {
        int take = cnt < 64 ? cnt : 64;
        u64 nk = (lane < take) ? buf[lane] : 0;
        nk = bitonic_sort64_desc(nk, lane);
        a = bitonic_merge_top64(a, nk, lane);
        t = __shfl(a, 20, 64);
        int rem = cnt - take;
        u64 mv = (lane < rem) ? buf[take + lane] : 0;
        if (lane < rem) buf[lane] = mv;
        cnt = rem;
    }

    if (lane < TOPK) idxT[lane * N_NODES + i] = (int)(~(unsigned)a);
}

// ---------------- K3: k_edge — es2T/ed2T [b][n] only (h never stored!) ------
__global__ __launch_bounds__(256) void k_edge(
    const float* __restrict__ x, const float* __restrict__ W,
    const float* __restrict__ Wb, const float* __restrict__ a_src,
    const float* __restrict__ a_dst, const float* __restrict__ emb,
    float* __restrict__ es2T, float* __restrict__ ed2T) {
    int wid = threadIdx.x >> 6, lane = threadIdx.x & 63;
    int gw = blockIdx.x * 4 + wid;
    const float* wp = W + lane * T_WIN;
    float w0 = wp[0], w1 = wp[1], w2 = wp[2], w3 = wp[3], w4 = wp[4];
    float bias = Wb[lane];
    float as = a_src[lane], asE = a_src[D_EMB + lane];
    float ad = a_dst[lane], adE = a_dst[D_EMB + lane];

    for (int node = gw; node < BN_TOTAL; node += 8192) {
        int n = node & (N_NODES - 1);
        const float* xp = x + (size_t)node * T_WIN;
        float hv = bias + xp[0] * w0 + xp[1] * w1 + xp[2] * w2 + xp[3] * w3 + xp[4] * w4;
        float e = emb[n * D_EMB + lane];
        float es = wave_sum(hv * as + e * asE);
        float ed = wave_sum(hv * ad + e * adE);
        if (lane == 0) {
            es2T[node] = es;   // node = b*N + n  -> [b][n] layout
            ed2T[node] = ed;
        }
    }
}

// ---------------- K3b: k_alpha — per-item softmax -> alphaT[b][k][i] --------
// ed2T[b][:] (8 KB) staged in LDS: the random neighbor gather hits LDS, not
// L2 (r5-r7 lesson: scattered global gathers retire ~1/wave despite unrolling).
// All idxT/alphaT accesses coalesce (k-major layout).
__global__ __launch_bounds__(256) void k_alpha(
    const int* __restrict__ idxT, const float* __restrict__ es2T,
    const float* __restrict__ ed2T, float* __restrict__ alphaT) {
    __shared__ float sed[N_NODES];   // 8 KB
    int g = blockIdx.x;
    int b = g & 31;
    int i0 = (g >> 5) * 256;
    int t = threadIdx.x;

    {
        const float4* src = (const float4*)(ed2T + (size_t)b * N_NODES);
        float4* dst = (float4*)sed;
#pragma unroll
        for (int q = 0; q < 2; q++) dst[t + 256 * q] = src[t + 256 * q];
    }
    __syncthreads();

    int i = i0 + t;
    float es = es2T[(size_t)b * N_NODES + i];
    float ev[TOPK];
    float m = -3e38f;
#pragma unroll
    for (int k = 0; k < TOPK; k++) {
        int jk = idxT[k * N_NODES + i];
        float e = es + sed[jk];
        e = e > 0.f ? e : NEG_SLOPE * e;
        ev[k] = e;
        m = fmaxf(m, e);
    }
    float s = 0.f;
#pragma unroll
    for (int k = 0; k < TOPK; k++) {
        ev[k] = __expf(ev[k] - m);
        s += ev[k];
    }
    float inv = 1.0f / s;
#pragma unroll
    for (int k = 0; k < TOPK; k++)
        alphaT[((size_t)b * TOPK + k) * N_NODES + i] = ev[k] * inv;
}

// ---------------- K4: message passing — LDS-resident h-tile -----------------
// Block = (b, d-chunk c of 4, half). The h-tile h[b][:,4c:4c+4] (32 KB) is
// computed FROM x IN-KERNEL into LDS (h never touches HBM). Gather is then
// ds_read_b128 (throughput ~12-17 cyc, latency-immune) + coalesced alphaT/
// idxT loads. XCD-local: xcd=g&7 owns batches {x,x+8,x+16,x+24}, all chunks.
__global__ __launch_bounds__(256, 4) void k_msg(
    const float* __restrict__ x, const float* __restrict__ W,
    const float* __restrict__ Wb, const int* __restrict__ idxT,
    const float* __restrict__ alphaT, const float* __restrict__ emb,
    float* __restrict__ obufT, float* __restrict__ stats,
    float* __restrict__ stats2) {
    __shared__ __align__(16) float hts[N_NODES][4];   // 32 KB
    __shared__ float sred[2][4][4];                    // [sum|sq][wave][q]

    int g = blockIdx.x;
    int b = (g & 7) + 8 * ((g >> 3) & 3);
    int rest = g >> 5;           // 0..31
    int c = rest & 15;           // d-chunk
    int half = rest >> 4;        // 0/1
    int d0 = c * 4;
    int t = threadIdx.x;
    int wid = t >> 6, lane = t & 63;

    // ---- build h-tile from x (redundant per half; 40K MAC, trivial) ----
    float wc[4][T_WIN], wb4[4];
#pragma unroll
    for (int q = 0; q < 4; q++) {
        wb4[q] = Wb[d0 + q];
#pragma unroll
        for (int tt = 0; tt < T_WIN; tt++) wc[q][tt] = W[(d0 + q) * T_WIN + tt];
    }
    const float* xb = x + (size_t)b * N_NODES * T_WIN;
#pragma unroll
    for (int r = 0; r < 8; r++) {
        int row = t + 256 * r;
        const float* xr = xb + row * T_WIN;
        float x0 = xr[0], x1 = xr[1], x2 = xr[2], x3 = xr[3], x4 = xr[4];
        float4 hv;
        hv.x = wb4[0] + x0 * wc[0][0] + x1 * wc[0][1] + x2 * wc[0][2] + x3 * wc[0][3] + x4 * wc[0][4];
        hv.y = wb4[1] + x0 * wc[1][0] + x1 * wc[1][1] + x2 * wc[1][2] + x3 * wc[1][3] + x4 * wc[1][4];
        hv.z = wb4[2] + x0 * wc[2][0] + x1 * wc[2][1] + x2 * wc[2][2] + x3 * wc[2][3] + x4 * wc[2][4];
        hv.w = wb4[3] + x0 * wc[3][0] + x1 * wc[3][1] + x2 * wc[3][2] + x3 * wc[3][3] + x4 * wc[3][4];
        *(float4*)&hts[row][0] = hv;
    }
    __syncthreads();

    // ---- gather: 1024 items (this half), 4 per thread ----
    float sacc[4] = {0.f, 0.f, 0.f, 0.f};
    float sacc2[4] = {0.f, 0.f, 0.f, 0.f};
    int ibase = half * 1024;
    const float* aT = alphaT + (size_t)b * TOPK * N_NODES;
#pragma unroll 1
    for (int r = 0; r < 4; r++) {
        int i = ibase + 256 * r + t;
        float4 z = make_float4(0.f, 0.f, 0.f, 0.f);
#pragma unroll
        for (int k = 0; k < TOPK; k++) {
            int jk = idxT[k * N_NODES + i];          // coalesced
            float a = aT[(size_t)k * N_NODES + i];   // coalesced
            float4 hv = *(const float4*)&hts[jk][0]; // LDS gather
            z.x = fmaf(a, hv.x, z.x);
            z.y = fmaf(a, hv.y, z.y);
            z.z = fmaf(a, hv.z, z.z);
            z.w = fmaf(a, hv.w, z.w);
        }
        const float* ep = emb + (size_t)i * D_EMB + d0;
        float4 e4 = *(const float4*)ep;
        float4 o;
        o.x = fmaxf(z.x, 0.f) * e4.x;
        o.y = fmaxf(z.y, 0.f) * e4.y;
        o.z = fmaxf(z.z, 0.f) * e4.z;
        o.w = fmaxf(z.w, 0.f) * e4.w;
        ((float4*)obufT)[((size_t)c * B_BATCH + b) * N_NODES + i] = o;
        sacc[0] += o.x; sacc[1] += o.y; sacc[2] += o.z; sacc[3] += o.w;
        sacc2[0] += o.x * o.x; sacc2[1] += o.y * o.y;
        sacc2[2] += o.z * o.z; sacc2[3] += o.w * o.w;
    }

    // ---- stats partials: wave reduce -> LDS -> 8 atomics/block ----
#pragma unroll
    for (int q = 0; q < 4; q++) {
        sacc[q] = wave_sum(sacc[q]);
        sacc2[q] = wave_sum(sacc2[q]);
    }
    if (lane == 0) {
#pragma unroll
        for (int q = 0; q < 4; q++) {
            sred[0][wid][q] = sacc[q];
            sred[1][wid][q] = sacc2[q];
        }
    }
    __syncthreads();
    if (t < 8) {
        int q = t & 3, which = t >> 2;
        float v = sred[which][0][q] + sred[which][1][q] + sred[which][2][q] + sred[which][3][q];
        float* dst = which ? stats2 : stats;
        atomicAdd(&dst[(d0 + q) * STATS_STRIDE], v);
    }
}

// ---------------- K5: BN apply + relu + fc (chunked obufT layout) -----------
// lane = nloc*16 + c: 16 c-lanes cover d=4c..4c+3; same-c lanes read 64 B
// contiguous (4 consecutive nodes) -> 16 full lines per wave-load.
__global__ __launch_bounds__(256) void k_out(
    const float* __restrict__ obufT, const float* __restrict__ stats,
    const float* __restrict__ stats2, const float* __restrict__ gamma,
    const float* __restrict__ beta, const float* __restrict__ fc_w,
    const float* __restrict__ fc_b, float* __restrict__ out) {
    int t = threadIdx.x;
    int wid = t >> 6, lane = t & 63;
    int nloc = lane >> 4, c = lane & 15;
    const float invM = 1.0f / (float)BN_TOTAL;

    float mean[4], inv[4], g4[4], bt4[4], fw4[4];
#pragma unroll
    for (int q = 0; q < 4; q++) {
        int d = 4 * c + q;
        float mn = stats[d * STATS_STRIDE] * invM;
        float var = stats2[d * STATS_STRIDE] * invM - mn * mn;
        mean[q] = mn;
        inv[q] = rsqrtf(var + EPS_BN);
        g4[q] = gamma[d]; bt4[q] = beta[d]; fw4[q] = fc_w[d];
    }
    float fb = fc_b[0];

#pragma unroll 1
    for (int r = 0; r < 16; r++) {
        int nd = blockIdx.x * 256 + r * 16 + wid * 4 + nloc;
        int b = nd >> 11, n = nd & (N_NODES - 1);
        float4 o = ((const float4*)obufT)[((size_t)c * B_BATCH + b) * N_NODES + n];
        float p = 0.f;
        float v;
        v = fmaxf((o.x - mean[0]) * inv[0] * g4[0] + bt4[0], 0.f); p = fmaf(v, fw4[0], p);
        v = fmaxf((o.y - mean[1]) * inv[1] * g4[1] + bt4[1], 0.f); p = fmaf(v, fw4[1], p);
        v = fmaxf((o.z - mean[2]) * inv[2] * g4[2] + bt4[2], 0.f); p = fmaf(v, fw4[2], p);
        v = fmaxf((o.w - mean[3]) * inv[3] * g4[3] + bt4[3], 0.f); p = fmaf(v, fw4[3], p);
#pragma unroll
        for (int off = 1; off <= 8; off <<= 1) p += __shfl_xor(p, off, 64);
        if (c == 0) out[nd] = p + fb;
    }
}

// ---------------- launch ----------------------------------------------------
extern "C" void kernel_launch(void* const* d_in, const int* in_sizes, int n_in,
                              void* d_out, int out_size, void* d_ws, size_t ws_size,
                              hipStream_t stream) {
    const float* x     = (const float*)d_in[0];
    const float* emb   = (const float*)d_in[1];
    const float* W     = (const float*)d_in[2];
    const float* Wb    = (const float*)d_in[3];
    const float* a_src = (const float*)d_in[4];
    const float* a_dst = (const float*)d_in[5];
    const float* gamma = (const float*)d_in[6];
    const float* beta  = (const float*)d_in[7];
    const float* fc_w  = (const float*)d_in[8];
    const float* fc_b  = (const float*)d_in[9];
    float* out = (float*)d_out;

    char* ws = (char*)d_ws;
    float* stats  = (float*)(ws + 0);             // 4 KB
    float* stats2 = (float*)(ws + 4096);          // 4 KB
    int*   idxT   = (int*)  (ws + 8192);          // 21*2048*4 = 172032 B
    float* norms  = (float*)(ws + 180224);        // 8 KB
    float* es2T   = (float*)(ws + 188416);        // 256 KB [b][n]
    float* ed2T   = (float*)(ws + 450560);        // 256 KB [b][n]
    float* alphaT = (float*)(ws + 712704);        // 32*21*2048*4 = 5505024 B
    float* cosM   = (float*)(ws + 6217728);       // 16 MB — aliased with obufT
    float* obufT  = cosM;                         // (cosM dead after k_select)
    // total: 22,994,944 bytes (h eliminated entirely)

    k_node_pre<<<N_NODES, 64, 0, stream>>>(emb, norms, stats, stats2);
    k_gram<<<1024, 256, 0, stream>>>(emb, norms, cosM);
    k_select<<<N_NODES / 4, 256, 0, stream>>>(cosM, idxT);
    k_edge<<<2048, 256, 0, stream>>>(x, W, Wb, a_src, a_dst, emb, es2T, ed2T);
    k_alpha<<<256, 256, 0, stream>>>(idxT, es2T, ed2T, alphaT);
    k_msg<<<1024, 256, 0, stream>>>(x, W, Wb, idxT, alphaT, emb, obufT, stats, stats2);
    k_out<<<256, 256, 0, stream>>>(obufT, stats, stats2, gamma, beta, fc_w, fc_b, out);
}

// Round 9
// 152.114 us; speedup vs baseline: 1.9345x; 1.0260x over previous
//
#include <hip/hip_runtime.h>
#include <math.h>

#define N_NODES 2048
#define T_WIN 5
#define D_EMB 64
#define TOPK 21
#define B_BATCH 32
#define BN_TOTAL (B_BATCH * N_NODES)   // 65536
#define EPS_BN 1e-5f
#define NEG_SLOPE 0.2f
#define STATS_STRIDE 16

typedef unsigned long long u64;

// ---------------- wave-level helpers (wave = 64 on gfx950) ----------------
__device__ __forceinline__ float wave_sum(float v) {
#pragma unroll
    for (int off = 32; off > 0; off >>= 1) v += __shfl_xor(v, off, 64);
    return v;
}

__device__ __forceinline__ u64 max64(u64 a, u64 b) { return a > b ? a : b; }
__device__ __forceinline__ u64 min64(u64 a, u64 b) { return a < b ? a : b; }

__device__ __forceinline__ u64 bitonic_sort64_desc(u64 key, int lane) {
#pragma unroll
    for (int k = 2; k <= 64; k <<= 1) {
#pragma unroll
        for (int j = k >> 1; j >= 1; j >>= 1) {
            u64 pk = __shfl_xor(key, j, 64);
            bool dirDesc = ((lane & k) == 0);
            bool keepMax = (((lane & j) == 0) == dirDesc);
            key = keepMax ? max64(key, pk) : min64(key, pk);
        }
    }
    return key;
}

__device__ __forceinline__ u64 bitonic_merge_top64(u64 a, u64 b, int lane) {
    u64 br = __shfl(b, 63 - lane, 64);
    u64 c = max64(a, br);
#pragma unroll
    for (int j = 32; j >= 1; j >>= 1) {
        u64 pk = __shfl_xor(c, j, 64);
        bool keepMax = ((lane & j) == 0);
        c = keepMax ? max64(c, pk) : min64(c, pk);
    }
    return c;
}

// ---------------- K1: k_edge — es2T/ed2T [b][n] + norms + stats zero --------
// Fused (r9): norms computed from the emb row this kernel already loads
// (identical expression to the old k_node_pre -> bit-identical; gram depends
// on it and launches after). Blocks 0/1 zero the stats buffers.
__global__ __launch_bounds__(256) void k_edge(
    const float* __restrict__ x, const float* __restrict__ W,
    const float* __restrict__ Wb, const float* __restrict__ a_src,
    const float* __restrict__ a_dst, const float* __restrict__ emb,
    float* __restrict__ es2T, float* __restrict__ ed2T,
    float* __restrict__ norms, float* __restrict__ stats,
    float* __restrict__ stats2) {
    if (blockIdx.x < 2) {
        float* p = blockIdx.x ? stats2 : stats;
        ((float4*)p)[threadIdx.x] = make_float4(0.f, 0.f, 0.f, 0.f);
    }
    int wid = threadIdx.x >> 6, lane = threadIdx.x & 63;
    int gw = blockIdx.x * 4 + wid;
    const float* wp = W + lane * T_WIN;
    float w0 = wp[0], w1 = wp[1], w2 = wp[2], w3 = wp[3], w4 = wp[4];
    float bias = Wb[lane];
    float as = a_src[lane], asE = a_src[D_EMB + lane];
    float ad = a_dst[lane], adE = a_dst[D_EMB + lane];

    for (int node = gw; node < BN_TOTAL; node += 8192) {
        int n = node & (N_NODES - 1);
        const float* xp = x + (size_t)node * T_WIN;
        float hv = bias + xp[0] * w0 + xp[1] * w1 + xp[2] * w2 + xp[3] * w3 + xp[4] * w4;
        float e = emb[n * D_EMB + lane];
        if (node < N_NODES) {                   // b==0 pass: also emit norms
            float s2 = wave_sum(e * e);
            if (lane == 0) norms[node] = sqrtf(s2);
        }
        float es = wave_sum(hv * as + e * asE);
        float ed = wave_sum(hv * ad + e * adE);
        if (lane == 0) {
            es2T[node] = es;   // node = b*N + n  -> [b][n] layout
            ed2T[node] = ed;
        }
    }
}

// ---------------- K2a: Gram/cos — upper-triangle blocks, symmetric write ----
// cos[i][j] == cos[j][i] bit-exactly here: the d-summation order is
// unchanged and fp mul commutes (a*b==b*a, ni*nj==nj*ni). So compute 528
// triangle tiles instead of 1024 and store each value to both [i][j] and
// [j][i]. Same write volume, half the staging + FMA + ds_read.
__global__ __launch_bounds__(256) void k_gram(
    const float* __restrict__ emb, const float* __restrict__ norms,
    float* __restrict__ cosM) {
    __shared__ __align__(16) float As[64][68];   // [d][i]
    __shared__ __align__(16) float Bs[64][68];   // [d][j]
    int t = threadIdx.x;
    int g = blockIdx.x;                          // 0..527
    int a = (int)((sqrtf(8.f * g + 1.f) - 1.f) * 0.5f);
    while ((a + 1) * (a + 2) / 2 <= g) a++;
    while (a * (a + 1) / 2 > g) a--;
    int bq = g - a * (a + 1) / 2;                // 0..a
    int i0 = a * 64, j0 = bq * 64;

    {
        int r = t >> 2, c0 = t & 3;
        const float4* srcA = (const float4*)(emb + (size_t)(i0 + r) * D_EMB);
        const float4* srcB = (const float4*)(emb + (size_t)(j0 + r) * D_EMB);
#pragma unroll
        for (int k = 0; k < 4; k++) {
            int f4 = c0 + 4 * k;
            float4 v = srcA[f4];
            int d = 4 * f4;
            As[d][r] = v.x; As[d + 1][r] = v.y; As[d + 2][r] = v.z; As[d + 3][r] = v.w;
            float4 w = srcB[f4];
            Bs[d][r] = w.x; Bs[d + 1][r] = w.y; Bs[d + 2][r] = w.z; Bs[d + 3][r] = w.w;
        }
    }
    __syncthreads();

    int ti = t & 15, tj = t >> 4;
    float acc[4][4] = {};
#pragma unroll
    for (int d = 0; d < 64; d++) {
        float4 av = *(const float4*)&As[d][4 * ti];
        float4 bv = *(const float4*)&Bs[d][4 * tj];
        acc[0][0] += av.x * bv.x; acc[0][1] += av.x * bv.y; acc[0][2] += av.x * bv.z; acc[0][3] += av.x * bv.w;
        acc[1][0] += av.y * bv.x; acc[1][1] += av.y * bv.y; acc[1][2] += av.y * bv.z; acc[1][3] += av.y * bv.w;
        acc[2][0] += av.z * bv.x; acc[2][1] += av.z * bv.y; acc[2][2] += av.z * bv.z; acc[2][3] += av.z * bv.w;
        acc[3][0] += av.w * bv.x; acc[3][1] += av.w * bv.y; acc[3][2] += av.w * bv.z; acc[3][3] += av.w * bv.w;
    }

    float nis[4] = {norms[i0 + 4 * ti], norms[i0 + 4 * ti + 1],
                    norms[i0 + 4 * ti + 2], norms[i0 + 4 * ti + 3]};
    float njs[4] = {norms[j0 + 4 * tj], norms[j0 + 4 * tj + 1],
                    norms[j0 + 4 * tj + 2], norms[j0 + 4 * tj + 3]};
#pragma unroll
    for (int r = 0; r < 4; r++) {
        float4 o;
        o.x = acc[r][0] / (nis[r] * njs[0]);
        o.y = acc[r][1] / (nis[r] * njs[1]);
        o.z = acc[r][2] / (nis[r] * njs[2]);
        o.w = acc[r][3] / (nis[r] * njs[3]);
        int i = i0 + 4 * ti + r;
        *(float4*)(cosM + (size_t)i * N_NODES + j0 + 4 * tj) = o;
        // transposed (bit-identical values)
        cosM[(size_t)(j0 + 4 * tj + 0) * N_NODES + i] = o.x;
        cosM[(size_t)(j0 + 4 * tj + 1) * N_NODES + i] = o.y;
        cosM[(size_t)(j0 + 4 * tj + 2) * N_NODES + i] = o.z;
        cosM[(size_t)(j0 + 4 * tj + 3) * N_NODES + i] = o.w;
    }
}

// ---------------- K2b: top-21 selection -> idxT[k][i] (transposed) ----------
__global__ __launch_bounds__(256) void k_select(
    const float* __restrict__ cosM, int* __restrict__ idxT) {
    __shared__ u64 candbuf[4][128];
    int tid = threadIdx.x;
    int wid = tid >> 6, lane = tid & 63;
    int i = blockIdx.x * 4 + wid;
    const float* row = cosM + (size_t)i * N_NODES;
    u64* buf = candbuf[wid];

    u64 a = 0;
    u64 t = 0;
    int cnt = 0;
    float vcur = row[lane];

#pragma unroll 1
    for (int c = 0; c < N_NODES / 64; c++) {
        int j = c * 64 + lane;
        float v = vcur;
        if (c < N_NODES / 64 - 1) vcur = row[j + 64];
        unsigned u = __float_as_uint(v);
        u = (u & 0x80000000u) ? ~u : (u | 0x80000000u);
        u64 key = ((u64)u << 32) | (unsigned)(~j);
        unsigned long long ball = __ballot(key > t);
        if (ball) {
            int ofs = __popcll(ball & ((1ull << lane) - 1ull));
            if (key > t) buf[cnt + ofs] = key;
            cnt += (int)__popcll(ball);
            if (cnt >= 64) {
                u64 nk = buf[lane];
                nk = bitonic_sort64_desc(nk, lane);
                a = bitonic_merge_top64(a, nk, lane);
                t = __shfl(a, 20, 64);
                int rem = cnt - 64;
                u64 mv = (lane < rem) ? buf[64 + lane] : 0;
                if (lane < rem) buf[lane] = mv;
                cnt = rem;
            }
        }
    }
    while (cnt > 0) {
        int take = cnt < 64 ? cnt : 64;
        u64 nk = (lane < take) ? buf[lane] : 0;
        nk = bitonic_sort64_desc(nk, lane);
        a = bitonic_merge_top64(a, nk, lane);
        t = __shfl(a, 20, 64);
        int rem = cnt - take;
        u64 mv = (lane < rem) ? buf[take + lane] : 0;
        if (lane < rem) buf[lane] = mv;
        cnt = rem;
    }

    if (lane < TOPK) idxT[lane * N_NODES + i] = (int)(~(unsigned)a);
}

// ---------------- K3: k_alpha — per-item softmax -> alphaT[b][k][i] ---------
__global__ __launch_bounds__(256) void k_alpha(
    const int* __restrict__ idxT, const float* __restrict__ es2T,
    const float* __restrict__ ed2T, float* __restrict__ alphaT) {
    __shared__ float sed[N_NODES];   // 8 KB
    int g = blockIdx.x;
    int b = g & 31;
    int i0 = (g >> 5) * 256;
    int t = threadIdx.x;

    {
        const float4* src = (const float4*)(ed2T + (size_t)b * N_NODES);
        float4* dst = (float4*)sed;
#pragma unroll
        for (int q = 0; q < 2; q++) dst[t + 256 * q] = src[t + 256 * q];
    }
    __syncthreads();

    int i = i0 + t;
    float es = es2T[(size_t)b * N_NODES + i];
    float ev[TOPK];
    float m = -3e38f;
#pragma unroll
    for (int k = 0; k < TOPK; k++) {
        int jk = idxT[k * N_NODES + i];
        float e = es + sed[jk];
        e = e > 0.f ? e : NEG_SLOPE * e;
        ev[k] = e;
        m = fmaxf(m, e);
    }
    float s = 0.f;
#pragma unroll
    for (int k = 0; k < TOPK; k++) {
        ev[k] = __expf(ev[k] - m);
        s += ev[k];
    }
    float inv = 1.0f / s;
#pragma unroll
    for (int k = 0; k < TOPK; k++)
        alphaT[((size_t)b * TOPK + k) * N_NODES + i] = ev[k] * inv;
}

// ---------------- K4: message passing — LDS h-tile, conflict-padded ---------
// Block = (b, d-chunk of 4). h-tile h[b][:,4c..4c+3] built from x in-LDS
// (h never in HBM). Row stride = 6 floats (24 B, 8B-aligned): gather via
// 2x ds_read_b64, start bank 6j%32 (gcd 2) -> ~4-way conflicts (1.58x,
// m136) vs r8's b128 16B-stride (start bank 4j%32, 8 groups -> ~8-way,
// 2.9x). Half-split removed: idx/alpha read once per (item,chunk).
__global__ __launch_bounds__(256, 2) void k_msg(
    const float* __restrict__ x, const float* __restrict__ W,
    const float* __restrict__ Wb, const int* __restrict__ idxT,
    const float* __restrict__ alphaT, const float* __restrict__ emb,
    float* __restrict__ obufT, float* __restrict__ stats,
    float* __restrict__ stats2) {
    __shared__ float hts[N_NODES][6];          // 48 KB, stride 24 B
    __shared__ float sred[2][4][4];

    int g = blockIdx.x;                        // 512 = 32 b x 16 c
    int b = (g & 7) + 8 * ((g >> 3) & 3);      // XCD-local batches
    int c = g >> 5;
    int d0 = c * 4;
    int t = threadIdx.x;
    int wid = t >> 6, lane = t & 63;

    // ---- build h-tile from x ----
    float wc[4][T_WIN], wb4[4];
#pragma unroll
    for (int q = 0; q < 4; q++) {
        wb4[q] = Wb[d0 + q];
#pragma unroll
        for (int tt = 0; tt < T_WIN; tt++) wc[q][tt] = W[(d0 + q) * T_WIN + tt];
    }
    const float* xb = x + (size_t)b * N_NODES * T_WIN;
#pragma unroll
    for (int r = 0; r < 8; r++) {
        int row = t + 256 * r;
        const float* xr = xb + row * T_WIN;
        float x0 = xr[0], x1 = xr[1], x2 = xr[2], x3 = xr[3], x4 = xr[4];
        float h0 = wb4[0] + x0 * wc[0][0] + x1 * wc[0][1] + x2 * wc[0][2] + x3 * wc[0][3] + x4 * wc[0][4];
        float h1 = wb4[1] + x0 * wc[1][0] + x1 * wc[1][1] + x2 * wc[1][2] + x3 * wc[1][3] + x4 * wc[1][4];
        float h2 = wb4[2] + x0 * wc[2][0] + x1 * wc[2][1] + x2 * wc[2][2] + x3 * wc[2][3] + x4 * wc[2][4];
        float h3 = wb4[3] + x0 * wc[3][0] + x1 * wc[3][1] + x2 * wc[3][2] + x3 * wc[3][3] + x4 * wc[3][4];
        *(float2*)&hts[row][0] = make_float2(h0, h1);
        *(float2*)&hts[row][2] = make_float2(h2, h3);
    }
    __syncthreads();

    // ---- gather: 2048 items, 8 per thread ----
    float sacc[4] = {0.f, 0.f, 0.f, 0.f};
    float sacc2[4] = {0.f, 0.f, 0.f, 0.f};
    const float* aT = alphaT + (size_t)b * TOPK * N_NODES;
#pragma unroll 1
    for (int r = 0; r < 8; r++) {
        int i = 256 * r + t;
        float4 z = make_float4(0.f, 0.f, 0.f, 0.f);
#pragma unroll
        for (int k = 0; k < TOPK; k++) {
            int jk = idxT[k * N_NODES + i];          // coalesced
            float a = aT[(size_t)k * N_NODES + i];   // coalesced
            float2 h01 = *(const float2*)&hts[jk][0];
            float2 h23 = *(const float2*)&hts[jk][2];
            z.x = fmaf(a, h01.x, z.x);
            z.y = fmaf(a, h01.y, z.y);
            z.z = fmaf(a, h23.x, z.z);
            z.w = fmaf(a, h23.y, z.w);
        }
        float4 e4 = *(const float4*)(emb + (size_t)i * D_EMB + d0);
        float4 o;
        o.x = fmaxf(z.x, 0.f) * e4.x;
        o.y = fmaxf(z.y, 0.f) * e4.y;
        o.z = fmaxf(z.z, 0.f) * e4.z;
        o.w = fmaxf(z.w, 0.f) * e4.w;
        ((float4*)obufT)[((size_t)c * B_BATCH + b) * N_NODES + i] = o;
        sacc[0] += o.x; sacc[1] += o.y; sacc[2] += o.z; sacc[3] += o.w;
        sacc2[0] += o.x * o.x; sacc2[1] += o.y * o.y;
        sacc2[2] += o.z * o.z; sacc2[3] += o.w * o.w;
    }

    // ---- stats partials ----
#pragma unroll
    for (int q = 0; q < 4; q++) {
        sacc[q] = wave_sum(sacc[q]);
        sacc2[q] = wave_sum(sacc2[q]);
    }
    if (lane == 0) {
#pragma unroll
        for (int q = 0; q < 4; q++) {
            sred[0][wid][q] = sacc[q];
            sred[1][wid][q] = sacc2[q];
        }
    }
    __syncthreads();
    if (t < 8) {
        int q = t & 3, which = t >> 2;
        float v = sred[which][0][q] + sred[which][1][q] + sred[which][2][q] + sred[which][3][q];
        float* dst = which ? stats2 : stats;
        atomicAdd(&dst[(d0 + q) * STATS_STRIDE], v);
    }
}

// ---------------- K5: BN apply + relu + fc (chunked obufT layout) -----------
__global__ __launch_bounds__(256) void k_out(
    const float* __restrict__ obufT, const float* __restrict__ stats,
    const float* __restrict__ stats2, const float* __restrict__ gamma,
    const float* __restrict__ beta, const float* __restrict__ fc_w,
    const float* __restrict__ fc_b, float* __restrict__ out) {
    int t = threadIdx.x;
    int wid = t >> 6, lane = t & 63;
    int nloc = lane >> 4, c = lane & 15;
    const float invM = 1.0f / (float)BN_TOTAL;

    float mean[4], inv[4], g4[4], bt4[4], fw4[4];
#pragma unroll
    for (int q = 0; q < 4; q++) {
        int d = 4 * c + q;
        float mn = stats[d * STATS_STRIDE] * invM;
        float var = stats2[d * STATS_STRIDE] * invM - mn * mn;
        mean[q] = mn;
        inv[q] = rsqrtf(var + EPS_BN);
        g4[q] = gamma[d]; bt4[q] = beta[d]; fw4[q] = fc_w[d];
    }
    float fb = fc_b[0];

#pragma unroll 1
    for (int r = 0; r < 8; r++) {
        int nd = blockIdx.x * 128 + r * 16 + wid * 4 + nloc;
        int b = nd >> 11, n = nd & (N_NODES - 1);
        float4 o = ((const float4*)obufT)[((size_t)c * B_BATCH + b) * N_NODES + n];
        float p = 0.f;
        float v;
        v = fmaxf((o.x - mean[0]) * inv[0] * g4[0] + bt4[0], 0.f); p = fmaf(v, fw4[0], p);
        v = fmaxf((o.y - mean[1]) * inv[1] * g4[1] + bt4[1], 0.f); p = fmaf(v, fw4[1], p);
        v = fmaxf((o.z - mean[2]) * inv[2] * g4[2] + bt4[2], 0.f); p = fmaf(v, fw4[2], p);
        v = fmaxf((o.w - mean[3]) * inv[3] * g4[3] + bt4[3], 0.f); p = fmaf(v, fw4[3], p);
#pragma unroll
        for (int off = 1; off <= 8; off <<= 1) p += __shfl_xor(p, off, 64);
        if (c == 0) out[nd] = p + fb;
    }
}

// ---------------- launch ----------------------------------------------------
extern "C" void kernel_launch(void* const* d_in, const int* in_sizes, int n_in,
                              void* d_out, int out_size, void* d_ws, size_t ws_size,
                              hipStream_t stream) {
    const float* x     = (const float*)d_in[0];
    const float* emb   = (const float*)d_in[1];
    const float* W     = (const float*)d_in[2];
    const float* Wb    = (const float*)d_in[3];
    const float* a_src = (const float*)d_in[4];
    const float* a_dst = (const float*)d_in[5];
    const float* gamma = (const float*)d_in[6];
    const float* beta  = (const float*)d_in[7];
    const float* fc_w  = (const float*)d_in[8];
    const float* fc_b  = (const float*)d_in[9];
    float* out = (float*)d_out;

    char* ws = (char*)d_ws;
    float* stats  = (float*)(ws + 0);             // 4 KB
    float* stats2 = (float*)(ws + 4096);          // 4 KB
    int*   idxT   = (int*)  (ws + 8192);          // 172032 B
    float* norms  = (float*)(ws + 180224);        // 8 KB
    float* es2T   = (float*)(ws + 188416);        // 256 KB [b][n]
    float* ed2T   = (float*)(ws + 450560);        // 256 KB [b][n]
    float* alphaT = (float*)(ws + 712704);        // 5505024 B [b][k][i]
    float* cosM   = (float*)(ws + 6217728);       // 16 MB — aliased with obufT
    float* obufT  = cosM;                         // (cosM dead after k_select)
    // total: 22,994,944 bytes

    k_edge<<<2048, 256, 0, stream>>>(x, W, Wb, a_src, a_dst, emb,
                                     es2T, ed2T, norms, stats, stats2);
    k_gram<<<528, 256, 0, stream>>>(emb, norms, cosM);
    k_select<<<N_NODES / 4, 256, 0, stream>>>(cosM, idxT);
    k_alpha<<<256, 256, 0, stream>>>(idxT, es2T, ed2T, alphaT);
    k_msg<<<512, 256, 0, stream>>>(x, W, Wb, idxT, alphaT, emb, obufT, stats, stats2);
    k_out<<<512, 256, 0, stream>>>(obufT, stats, stats2, gamma, beta, fc_w, fc_b, out);
}